// Round 9
// baseline (3593.826 us; speedup 1.0000x reference)
//
#include <hip/hip_runtime.h>
#include <hip/hip_bf16.h>

#define E_TOTAL 500000
#define TILE 128
#define NTILES ((E_TOTAL + TILE - 1) / TILE)   // 3907
#define NBLOCKS 256

typedef __attribute__((ext_vector_type(8))) short bf16x8;
typedef __attribute__((ext_vector_type(4))) float f32x4;

// D = A*B + C ; A rows -> C rows (features), B cols -> C cols (edges)
#define MFMA(a, b, c) __builtin_amdgcn_mfma_f32_16x16x32_bf16((a), (b), (c), 0, 0, 0)

// Barrier with LDS-only drain: global loads/stores stay in flight.
__device__ __forceinline__ void lbar() {
    asm volatile("s_waitcnt lgkmcnt(0)" ::: "memory");
    __builtin_amdgcn_s_barrier();
}
// compile-time ordering fence for aliased LDS phases (no instruction emitted)
__device__ __forceinline__ void cfence() { asm volatile("" ::: "memory"); }

__device__ __forceinline__ unsigned short f2b(float f) {
    return __builtin_bit_cast(unsigned short, __float2bfloat16(f));
}
__device__ __forceinline__ float b2f(unsigned short s) {
    return __bfloat162float(__builtin_bit_cast(__hip_bfloat16, s));
}
__device__ __forceinline__ float sigm(float x) { return 1.f / (1.f + __expf(-x)); }
__device__ __forceinline__ float tanh_fast(float x) {
    float t = __expf(-2.f * x);
    return (1.f - t) / (1.f + t);
}
// XOR-swizzled LDS address (T2)
__device__ __forceinline__ char* swzp(void* base, int row, int rowBytes, int colByte) {
    return (char*)base + row * rowBytes + (colByte ^ ((row & 7) << 4));
}

// f32 -> bf16 weight pre-conversion into workspace (runs every call; cheap).
__global__ void wconv_kernel(const float* __restrict__ W1, const float* __restrict__ Wih,
                             const float* __restrict__ Whh, const float* __restrict__ Wx,
                             unsigned short* __restrict__ out) {
    int i = blockIdx.x * 256 + threadIdx.x;
    if (i >= 155648) return;
    float v;
    if      (i < 49152)  v = W1[i];
    else if (i < 98304)  v = Wih[i - 49152];
    else if (i < 147456) v = Whh[i - 98304];
    else                 v = Wx[i - 147456];
    out[i] = f2b(v);
}

// LDS 138496 B (1 block/CU). Per row e: x1[e] 768B holds concat input;
// after GEMM1 the wave that OWNS row e overwrites bytes [0,256) with y
// and bytes [512,768) with hnew — all rows of a wave are private to it,
// so no cross-wave barrier is needed between compute phases.
struct Smem {
    unsigned short x1[TILE][384];   // 98304
    unsigned short hbf[TILE][128];  // 32768
    float par[1856];                // 7424: b1,g1,beta1,bih,bhh,bx,Ww,bw,gw,betaw
};

__global__ __launch_bounds__(512, 1) void edge_model_kernel(
    const float* __restrict__ src, const float* __restrict__ dst,
    const float* __restrict__ eat, const float* __restrict__ hin,
    const float* __restrict__ u, const int* __restrict__ batch,
    const float* __restrict__ winding,
    const float* __restrict__ Ww, const float* __restrict__ bw,
    const float* __restrict__ gw, const float* __restrict__ betaw,
    const float* __restrict__ b1, const float* __restrict__ g1,
    const float* __restrict__ beta1,
    const float* __restrict__ bih, const float* __restrict__ bhh,
    const float* __restrict__ bx,
    const unsigned short* __restrict__ W1bf, const unsigned short* __restrict__ Wihbf,
    const unsigned short* __restrict__ Whhbf, const unsigned short* __restrict__ Wxbf,
    float* __restrict__ xout, float* __restrict__ hout)
{
    __shared__ Smem sm;
    const int tid  = threadIdx.x;
    const int wave = tid >> 6;        // 0..7; owns EDGES [16w, 16w+16)
    const int lane = tid & 63;
    const int lhi  = lane >> 4;       // 0..3
    const int llo  = lane & 15;       // 0..15
    const int erow = wave * 16 + llo; // this lane's edge row (B-frag row & epilogue edge)

    // ---- stage params into LDS once per block ----
    for (int i = tid; i < 1856; i += 512) {
        float v;
        if      (i < 128)  v = b1[i];
        else if (i < 256)  v = g1[i - 128];
        else if (i < 384)  v = beta1[i - 256];
        else if (i < 768)  v = bih[i - 384];
        else if (i < 1152) v = bhh[i - 768];
        else if (i < 1216) v = bx[i - 1152];
        else if (i < 1472) v = Ww[i - 1216];
        else if (i < 1600) v = bw[i - 1472];
        else if (i < 1728) v = gw[i - 1600];
        else               v = betaw[i - 1728];
        sm.par[i] = v;
    }
    lbar();

    for (int tile = blockIdx.x; tile < NTILES; tile += NBLOCKS) {
        const size_t e0 = (size_t)tile * TILE;

        // ---------------- staging: x1 cols 0..255 + h tile + winding MLP ----------------
        #pragma unroll
        for (int it = 0; it < 4; ++it) {
            int q   = it * 512 + tid;            // 2048 float4-quads
            int row = q >> 4;
            int c4  = (q & 15) << 2;
            size_t e = e0 + row; if (e >= E_TOTAL) e = E_TOTAL - 1;
            float4 a = *(const float4*)(src + e * 64 + c4);
            float4 b = *(const float4*)(dst + e * 64 + c4);
            float4 c = *(const float4*)(eat + e * 64 + c4);
            int bi   = batch[e];
            float4 d = *(const float4*)(u + (size_t)bi * 64 + c4);
            ushort4 pa; pa.x=f2b(a.x); pa.y=f2b(a.y); pa.z=f2b(a.z); pa.w=f2b(a.w);
            ushort4 pb; pb.x=f2b(b.x); pb.y=f2b(b.y); pb.z=f2b(b.z); pb.w=f2b(b.w);
            ushort4 pc; pc.x=f2b(c.x); pc.y=f2b(c.y); pc.z=f2b(c.z); pc.w=f2b(c.w);
            ushort4 pd; pd.x=f2b(d.x); pd.y=f2b(d.y); pd.z=f2b(d.z); pd.w=f2b(d.w);
            *(ushort4*)swzp(sm.x1, row, 768, 2 * c4)       = pa;
            *(ushort4*)swzp(sm.x1, row, 768, 128 + 2 * c4) = pb;
            *(ushort4*)swzp(sm.x1, row, 768, 256 + 2 * c4) = pc;
            *(ushort4*)swzp(sm.x1, row, 768, 384 + 2 * c4) = pd;
        }
        #pragma unroll
        for (int it = 0; it < 8; ++it) {
            int q   = it * 512 + tid;            // 4096 float4-quads
            int row = q >> 5;
            int c4  = (q & 31) << 2;
            size_t e = e0 + row; if (e >= E_TOTAL) e = E_TOTAL - 1;
            float4 v = *(const float4*)(hin + e * 128 + c4);
            ushort4 p; p.x=f2b(v.x); p.y=f2b(v.y); p.z=f2b(v.z); p.w=f2b(v.w);
            *(ushort4*)swzp(sm.hbf, row, 256, 2 * c4) = p;
        }
        {   // winding MLP: Linear(2->128)+LN+ReLU, 4 threads/row, params from LDS
            int row = tid >> 2;
            int seg = tid & 3;
            size_t e = e0 + row; if (e >= E_TOTAL) e = E_TOTAL - 1;
            float wi0 = winding[e * 2], wi1 = winding[e * 2 + 1];
            float vals[32]; float s = 0.f, s2 = 0.f;
            #pragma unroll
            for (int j = 0; j < 32; ++j) {
                int jj = seg * 32 + j;
                float v = fmaf(wi0, sm.par[1216 + 2 * jj],
                          fmaf(wi1, sm.par[1216 + 2 * jj + 1], sm.par[1472 + jj]));
                vals[j] = v; s += v; s2 += v * v;
            }
            s  += __shfl_xor(s, 1);  s  += __shfl_xor(s, 2);
            s2 += __shfl_xor(s2, 1); s2 += __shfl_xor(s2, 2);
            float mean = s * (1.f / 128.f);
            float var  = fmaxf(s2 * (1.f / 128.f) - mean * mean, 0.f);
            float inv  = rsqrtf(var + 1e-5f);
            #pragma unroll
            for (int j4 = 0; j4 < 8; ++j4) {
                ushort4 pk;
                #pragma unroll
                for (int j = 0; j < 4; ++j) {
                    int jj = seg * 32 + j4 * 4 + j;
                    float v = (vals[j4 * 4 + j] - mean) * inv * sm.par[1600 + jj] + sm.par[1728 + jj];
                    ((unsigned short*)&pk)[j] = f2b(fmaxf(v, 0.f));
                }
                *(ushort4*)swzp(sm.x1, row, 768, 512 + seg * 64 + j4 * 8) = pk;
            }
        }
        lbar();   // (1) staging complete — everything below is wave-private

        // ---------------- GEMM1: acc[nt] = W1 @ x1^T for own 16 edges, all 128 feats ----------------
        f32x4 acc[8];
        #pragma unroll
        for (int nt = 0; nt < 8; ++nt) acc[nt] = (f32x4){0.f, 0.f, 0.f, 0.f};
        for (int ks = 0; ks < 12; ++ks) {
            bf16x8 xf = *(const bf16x8*)swzp(sm.x1, erow, 768, ks * 64 + lhi * 16);
            const unsigned short* wp = W1bf + (size_t)llo * 384 + ks * 32 + lhi * 8;
            #pragma unroll
            for (int nt = 0; nt < 8; ++nt) {
                bf16x8 wf = *(const bf16x8*)(wp + nt * 16 * 384);
                acc[nt] = MFMA(wf, xf, acc[nt]);
            }
        }
        // bias + in-wave LN over 128 features (8 regs x 4 + shfl over lhi)
        {
            float s = 0.f, s2 = 0.f;
            #pragma unroll
            for (int nt = 0; nt < 8; ++nt) {
                float4 bq = *(const float4*)&sm.par[nt * 16 + lhi * 4];
                #pragma unroll
                for (int r = 0; r < 4; ++r) {
                    float v = acc[nt][r] + ((const float*)&bq)[r];
                    acc[nt][r] = v; s += v; s2 += v * v;
                }
            }
            s  += __shfl_xor(s, 16);  s  += __shfl_xor(s, 32);
            s2 += __shfl_xor(s2, 16); s2 += __shfl_xor(s2, 32);
            float mean = s * (1.f / 128.f);
            float var  = fmaxf(s2 * (1.f / 128.f) - mean * mean, 0.f);
            float inv  = rsqrtf(var + 1e-5f);
            cfence();   // all x1[erow] k-reads above stay before the y overwrite below
            #pragma unroll
            for (int nt = 0; nt < 8; ++nt) {
                int f = nt * 16 + lhi * 4;
                float4 gq  = *(const float4*)&sm.par[128 + f];
                float4 beq = *(const float4*)&sm.par[256 + f];
                ushort4 pk;
                #pragma unroll
                for (int r = 0; r < 4; ++r) {
                    float v = (acc[nt][r] - mean) * inv * ((const float*)&gq)[r] + ((const float*)&beq)[r];
                    ((unsigned short*)&pk)[r] = f2b(fmaxf(v, 0.f));
                }
                *(ushort4*)swzp(sm.x1, erow, 768, 2 * f) = pk;   // y -> bytes [0,256)
            }
        }
        cfence();

        // ---------------- GRU: all 384 gate rows for own 16 edges, 2 feature-half passes ----------------
        #pragma unroll
        for (int ph = 0; ph < 2; ++ph) {
            f32x4 ar[4], az[4], an_[4], ah_[4];
            #pragma unroll
            for (int t = 0; t < 4; ++t) {
                ar[t] = (f32x4){0.f,0.f,0.f,0.f}; az[t] = (f32x4){0.f,0.f,0.f,0.f};
                an_[t] = (f32x4){0.f,0.f,0.f,0.f}; ah_[t] = (f32x4){0.f,0.f,0.f,0.f};
            }
            for (int ks = 0; ks < 4; ++ks) {
                bf16x8 ay = *(const bf16x8*)swzp(sm.x1, erow, 768, ks * 64 + lhi * 16);
                bf16x8 ah = *(const bf16x8*)swzp(sm.hbf, erow, 256, ks * 64 + lhi * 16);
                const unsigned short* pi = Wihbf + (size_t)(ph * 64 + llo) * 128 + ks * 32 + lhi * 8;
                const unsigned short* pw = Whhbf + (size_t)(ph * 64 + llo) * 128 + ks * 32 + lhi * 8;
                #pragma unroll
                for (int t = 0; t < 4; ++t) {
                    const size_t ro = (size_t)t * 16 * 128;
                    bf16x8 wr = *(const bf16x8*)(pi + ro);
                    bf16x8 wz = *(const bf16x8*)(pi + 128 * 128 + ro);
                    bf16x8 wn = *(const bf16x8*)(pi + 256 * 128 + ro);
                    bf16x8 vr = *(const bf16x8*)(pw + ro);
                    bf16x8 vz = *(const bf16x8*)(pw + 128 * 128 + ro);
                    bf16x8 vn = *(const bf16x8*)(pw + 256 * 128 + ro);
                    ar[t]  = MFMA(wr, ay, ar[t]);   ar[t]  = MFMA(vr, ah, ar[t]);
                    az[t]  = MFMA(wz, ay, az[t]);   az[t]  = MFMA(vz, ah, az[t]);
                    an_[t] = MFMA(wn, ay, an_[t]);  ah_[t] = MFMA(vn, ah, ah_[t]);
                }
            }
            cfence();
            #pragma unroll
            for (int t = 0; t < 4; ++t) {
                int f = ph * 64 + t * 16 + lhi * 4;
                float4 bi0 = *(const float4*)&sm.par[384 + f];
                float4 bi1 = *(const float4*)&sm.par[384 + 128 + f];
                float4 bi2 = *(const float4*)&sm.par[384 + 256 + f];
                float4 bh0 = *(const float4*)&sm.par[768 + f];
                float4 bh1 = *(const float4*)&sm.par[768 + 128 + f];
                float4 bh2 = *(const float4*)&sm.par[768 + 256 + f];
                ushort4 hp = *(const ushort4*)swzp(sm.hbf, erow, 256, 2 * f);
                ushort4 pk; float4 ho;
                #pragma unroll
                for (int r = 0; r < 4; ++r) {
                    float rr = sigm(ar[t][r] + ((const float*)&bi0)[r] + ((const float*)&bh0)[r]);
                    float zz = sigm(az[t][r] + ((const float*)&bi1)[r] + ((const float*)&bh1)[r]);
                    float nn = tanh_fast(an_[t][r] + ((const float*)&bi2)[r]
                                         + rr * (ah_[t][r] + ((const float*)&bh2)[r]));
                    float hv = b2f(((const unsigned short*)&hp)[r]);
                    float hnv = (1.f - zz) * nn + zz * hv;
                    ((unsigned short*)&pk)[r] = f2b(hnv);
                    ((float*)&ho)[r] = hnv;
                }
                *(ushort4*)swzp(sm.x1, erow, 768, 512 + 2 * f) = pk;   // hnew -> bytes [512,768)
                size_t e = e0 + erow;
                if (e < E_TOTAL) *(float4*)(hout + e * 128 + f) = ho;  // 4-lane 64B sectors
            }
            cfence();
        }

        // ---------------- GEMM3: xout = Wx @ hnew^T for own 16 edges ----------------
        {
            f32x4 a3[4];
            #pragma unroll
            for (int ft = 0; ft < 4; ++ft) a3[ft] = (f32x4){0.f, 0.f, 0.f, 0.f};
            for (int ks = 0; ks < 4; ++ks) {
                bf16x8 bh = *(const bf16x8*)swzp(sm.x1, erow, 768, 512 + ks * 64 + lhi * 16);
                const unsigned short* px = Wxbf + (size_t)llo * 128 + ks * 32 + lhi * 8;
                #pragma unroll
                for (int ft = 0; ft < 4; ++ft) {
                    bf16x8 wf = *(const bf16x8*)(px + (size_t)ft * 16 * 128);
                    a3[ft] = MFMA(wf, bh, a3[ft]);
                }
            }
            #pragma unroll
            for (int ft = 0; ft < 4; ++ft) {
                int fx = ft * 16 + lhi * 4;
                float4 bq = *(const float4*)&sm.par[1152 + fx];
                float4 o;
                o.x = a3[ft][0] + bq.x; o.y = a3[ft][1] + bq.y;
                o.z = a3[ft][2] + bq.z; o.w = a3[ft][3] + bq.w;
                size_t e = e0 + erow;
                if (e < E_TOTAL) *(float4*)(xout + e * 64 + fx) = o;   // 4-lane 64B sectors
            }
        }
        lbar();   // (2) all reads of x1/hbf done -> next tile may overwrite
    }
}

extern "C" void kernel_launch(void* const* d_in, const int* in_sizes, int n_in,
                              void* d_out, int out_size, void* d_ws, size_t ws_size,
                              hipStream_t stream)
{
    const float* src   = (const float*)d_in[0];
    const float* dst   = (const float*)d_in[1];
    const float* eat   = (const float*)d_in[2];
    const float* hin   = (const float*)d_in[3];
    const float* u     = (const float*)d_in[4];
    const int*   bat   = (const int*)d_in[5];
    const float* wind  = (const float*)d_in[6];
    const float* Ww    = (const float*)d_in[7];
    const float* bw    = (const float*)d_in[8];
    const float* gw    = (const float*)d_in[9];
    const float* betaw = (const float*)d_in[10];
    const float* W1    = (const float*)d_in[11];
    const float* b1    = (const float*)d_in[12];
    const float* g1    = (const float*)d_in[13];
    const float* beta1 = (const float*)d_in[14];
    const float* Wih   = (const float*)d_in[15];
    const float* Whh   = (const float*)d_in[16];
    const float* bih   = (const float*)d_in[17];
    const float* bhh   = (const float*)d_in[18];
    const float* Wx    = (const float*)d_in[19];
    const float* bx    = (const float*)d_in[20];

    unsigned short* wbuf = (unsigned short*)d_ws;   // 155648 bf16 = 304 KB
    wconv_kernel<<<608, 256, 0, stream>>>(W1, Wih, Whh, Wx, wbuf);

    float* xout = (float*)d_out;
    float* hout = xout + (size_t)E_TOTAL * 64;
    edge_model_kernel<<<NBLOCKS, 512, 0, stream>>>(
        src, dst, eat, hin, u, bat, wind, Ww, bw, gw, betaw,
        b1, g1, beta1, bih, bhh, bx,
        wbuf, wbuf + 49152, wbuf + 98304, wbuf + 147456,
        xout, hout);
}

// Round 10
// 1114.485 us; speedup vs baseline: 3.2247x; 3.2247x over previous
//
#include <hip/hip_runtime.h>
#include <hip/hip_bf16.h>

#define E_TOTAL 500000
#define TILE 32
#define NTILES (E_TOTAL / TILE)   // 15625, exact
#define NBLOCKS 768               // 3 blocks/CU target

typedef __attribute__((ext_vector_type(8))) short bf16x8;
typedef __attribute__((ext_vector_type(4))) float f32x4;

// D = A*B + C ; A rows -> C rows (features), B cols -> C cols (edges)
#define MFMA(a, b, c) __builtin_amdgcn_mfma_f32_16x16x32_bf16((a), (b), (c), 0, 0, 0)

// Barrier with LDS-only drain: global loads/stores stay in flight.
__device__ __forceinline__ void lbar() {
    asm volatile("s_waitcnt lgkmcnt(0)" ::: "memory");
    __builtin_amdgcn_s_barrier();
}

__device__ __forceinline__ unsigned short f2b(float f) {
    return __builtin_bit_cast(unsigned short, __float2bfloat16(f));
}
__device__ __forceinline__ float b2f(unsigned short s) {
    return __bfloat162float(__builtin_bit_cast(__hip_bfloat16, s));
}
__device__ __forceinline__ float sigm(float x) { return 1.f / (1.f + __expf(-x)); }
__device__ __forceinline__ float tanh_fast(float x) {
    float t = __expf(-2.f * x);
    return (1.f - t) / (1.f + t);
}
// XOR-swizzled LDS address (T2)
__device__ __forceinline__ char* swzp(void* base, int row, int rowBytes, int colByte) {
    return (char*)base + row * rowBytes + (colByte ^ ((row & 7) << 4));
}

// f32 -> bf16 weight pre-conversion into workspace (runs every call; cheap).
__global__ void wconv_kernel(const float* __restrict__ W1, const float* __restrict__ Wih,
                             const float* __restrict__ Whh, const float* __restrict__ Wx,
                             unsigned short* __restrict__ out) {
    int i = blockIdx.x * 256 + threadIdx.x;
    if (i >= 155648) return;
    float v;
    if      (i < 49152)  v = W1[i];
    else if (i < 98304)  v = Wih[i - 49152];
    else if (i < 147456) v = Whh[i - 98304];
    else                 v = Wx[i - 147456];
    out[i] = f2b(v);
}

// LDS 43264 B -> 3 blocks/CU. All tiles XOR-swizzled, pad-free strides.
struct Smem {
    union {
        unsigned short x1[TILE][384];                     // 24576, staging -> GEMM1
        struct { unsigned short y[TILE][128];             // [0,8192)    GEMM1-out -> GRU
                 unsigned short hnew[TILE][128]; } p;     // [8192,16384) GRU-out -> GEMM3
    } u;
    unsigned short hbf[TILE][128];                        // 8192, h tile bf16
    float lns[TILE][12];                                  // 1536
    float ln2[TILE][12];                                  // 1536
    float par[1856];                                      // 7424: b1,g1,beta1,bih,bhh,bx,Ww,bw,gw,betaw
};

__global__ __launch_bounds__(256, 1) void edge_model_kernel(
    const float* __restrict__ src, const float* __restrict__ dst,
    const float* __restrict__ eat, const float* __restrict__ hin,
    const float* __restrict__ u, const int* __restrict__ batch,
    const float* __restrict__ winding,
    const float* __restrict__ Ww, const float* __restrict__ bw,
    const float* __restrict__ gw, const float* __restrict__ betaw,
    const float* __restrict__ b1, const float* __restrict__ g1,
    const float* __restrict__ beta1,
    const float* __restrict__ bih, const float* __restrict__ bhh,
    const float* __restrict__ bx,
    const unsigned short* __restrict__ W1bf, const unsigned short* __restrict__ Wihbf,
    const unsigned short* __restrict__ Whhbf, const unsigned short* __restrict__ Wxbf,
    float* __restrict__ xout, float* __restrict__ hout)
{
    __shared__ Smem sm;
    const int tid  = threadIdx.x;
    const int wave = tid >> 6;        // 0..3; owns FEATURE rows [32w, 32w+32)
    const int lane = tid & 63;
    const int lhi  = lane >> 4;       // 0..3
    const int llo  = lane & 15;       // 0..15

    // ---- stage params into LDS once per block ----
    for (int i = tid; i < 1856; i += 256) {
        float v;
        if      (i < 128)  v = b1[i];
        else if (i < 256)  v = g1[i - 128];
        else if (i < 384)  v = beta1[i - 256];
        else if (i < 768)  v = bih[i - 384];
        else if (i < 1152) v = bhh[i - 768];
        else if (i < 1216) v = bx[i - 1152];
        else if (i < 1472) v = Ww[i - 1216];
        else if (i < 1600) v = bw[i - 1472];
        else if (i < 1728) v = gw[i - 1600];
        else               v = betaw[i - 1728];
        sm.par[i] = v;
    }
    lbar();

    for (int tile = blockIdx.x; tile < NTILES; tile += NBLOCKS) {
        const size_t e0 = (size_t)tile * TILE;

        // ---------------- staging: x1 cols 0..255 + h + winding MLP (swizzled) ----------------
        #pragma unroll
        for (int it = 0; it < 2; ++it) {
            int q   = it * 256 + tid;            // 512 float4-quads
            int row = q >> 4;
            int c4  = (q & 15) << 2;
            size_t e = e0 + row;
            float4 a = *(const float4*)(src + e * 64 + c4);
            float4 b = *(const float4*)(dst + e * 64 + c4);
            float4 c = *(const float4*)(eat + e * 64 + c4);
            int bi   = batch[e];
            float4 d = *(const float4*)(u + (size_t)bi * 64 + c4);
            ushort4 pa; pa.x=f2b(a.x); pa.y=f2b(a.y); pa.z=f2b(a.z); pa.w=f2b(a.w);
            ushort4 pb; pb.x=f2b(b.x); pb.y=f2b(b.y); pb.z=f2b(b.z); pb.w=f2b(b.w);
            ushort4 pc; pc.x=f2b(c.x); pc.y=f2b(c.y); pc.z=f2b(c.z); pc.w=f2b(c.w);
            ushort4 pd; pd.x=f2b(d.x); pd.y=f2b(d.y); pd.z=f2b(d.z); pd.w=f2b(d.w);
            *(ushort4*)swzp(sm.u.x1, row, 768, 2 * c4)       = pa;
            *(ushort4*)swzp(sm.u.x1, row, 768, 128 + 2 * c4) = pb;
            *(ushort4*)swzp(sm.u.x1, row, 768, 256 + 2 * c4) = pc;
            *(ushort4*)swzp(sm.u.x1, row, 768, 384 + 2 * c4) = pd;
        }
        #pragma unroll
        for (int it = 0; it < 4; ++it) {
            int q   = it * 256 + tid;            // 1024 float4-quads
            int row = q >> 5;
            int c4  = (q & 31) << 2;
            size_t e = e0 + row;
            float4 v = *(const float4*)(hin + e * 128 + c4);
            ushort4 p; p.x=f2b(v.x); p.y=f2b(v.y); p.z=f2b(v.z); p.w=f2b(v.w);
            *(ushort4*)swzp(sm.hbf, row, 256, 2 * c4) = p;
        }
        {   // winding MLP: Linear(2->128)+LN+ReLU, 8 threads/row, params from LDS
            int row = tid >> 3;
            int seg = tid & 7;
            size_t e = e0 + row;
            float wi0 = winding[e * 2], wi1 = winding[e * 2 + 1];
            float vals[16]; float s = 0.f, s2 = 0.f;
            #pragma unroll
            for (int j = 0; j < 16; ++j) {
                int jj = seg * 16 + j;
                float v = fmaf(wi0, sm.par[1216 + 2 * jj],
                          fmaf(wi1, sm.par[1216 + 2 * jj + 1], sm.par[1472 + jj]));
                vals[j] = v; s += v; s2 += v * v;
            }
            s  += __shfl_xor(s, 1);  s  += __shfl_xor(s, 2);  s  += __shfl_xor(s, 4);
            s2 += __shfl_xor(s2, 1); s2 += __shfl_xor(s2, 2); s2 += __shfl_xor(s2, 4);
            float mean = s * (1.f / 128.f);
            float var  = fmaxf(s2 * (1.f / 128.f) - mean * mean, 0.f);
            float inv  = rsqrtf(var + 1e-5f);
            #pragma unroll
            for (int j4 = 0; j4 < 4; ++j4) {
                ushort4 pk;
                #pragma unroll
                for (int j = 0; j < 4; ++j) {
                    int jj = seg * 16 + j4 * 4 + j;
                    float v = (vals[j4 * 4 + j] - mean) * inv * sm.par[1600 + jj] + sm.par[1728 + jj];
                    ((unsigned short*)&pk)[j] = f2b(fmaxf(v, 0.f));
                }
                *(ushort4*)swzp(sm.u.x1, row, 768, 512 + seg * 32 + j4 * 8) = pk;
            }
        }
        lbar();   // (1) staging complete

        // ---------------- GEMM1: acc[nt][mt] = W1[32w+16nt..] @ x1^T[edges 16mt..] ----------------
        f32x4 acc[2][2];
        acc[0][0] = (f32x4){0.f,0.f,0.f,0.f}; acc[0][1] = (f32x4){0.f,0.f,0.f,0.f};
        acc[1][0] = (f32x4){0.f,0.f,0.f,0.f}; acc[1][1] = (f32x4){0.f,0.f,0.f,0.f};
        {
            const unsigned short* wp = W1bf + (size_t)(wave * 32 + llo) * 384 + lhi * 8;
            #pragma unroll
            for (int ks = 0; ks < 12; ++ks) {
                bf16x8 xf0 = *(const bf16x8*)swzp(sm.u.x1, llo,      768, ks * 64 + lhi * 16);
                bf16x8 xf1 = *(const bf16x8*)swzp(sm.u.x1, 16 + llo, 768, ks * 64 + lhi * 16);
                bf16x8 wf0 = *(const bf16x8*)(wp + ks * 32);
                bf16x8 wf1 = *(const bf16x8*)(wp + 16 * 384 + ks * 32);
                acc[0][0] = MFMA(wf0, xf0, acc[0][0]);
                acc[0][1] = MFMA(wf0, xf1, acc[0][1]);
                acc[1][0] = MFMA(wf1, xf0, acc[1][0]);
                acc[1][1] = MFMA(wf1, xf1, acc[1][1]);
            }
        }
        {   // bias + per-wave LN partials over this wave's 32 features
            #pragma unroll
            for (int mt = 0; mt < 2; ++mt) {
                float s = 0.f, s2 = 0.f;
                #pragma unroll
                for (int nt = 0; nt < 2; ++nt) {
                    float4 bq = *(const float4*)&sm.par[wave * 32 + nt * 16 + lhi * 4];
                    #pragma unroll
                    for (int r = 0; r < 4; ++r) {
                        float v = acc[nt][mt][r] + ((const float*)&bq)[r];
                        acc[nt][mt][r] = v; s += v; s2 += v * v;
                    }
                }
                s  += __shfl_xor(s, 16);  s  += __shfl_xor(s, 32);
                s2 += __shfl_xor(s2, 16); s2 += __shfl_xor(s2, 32);
                if (lane < 16) { sm.lns[mt * 16 + llo][wave] = s; sm.ln2[mt * 16 + llo][wave] = s2; }
            }
        }
        lbar();   // (2) x1 reads done + LN partials ready -> y may alias x1

        {   // LN apply + ReLU + packed y write
            #pragma unroll
            for (int mt = 0; mt < 2; ++mt) {
                int edge = mt * 16 + llo;
                float4 sa = *(const float4*)&sm.lns[edge][0];
                float4 ta = *(const float4*)&sm.ln2[edge][0];
                float s  = sa.x + sa.y + sa.z + sa.w;
                float s2 = ta.x + ta.y + ta.z + ta.w;
                float mean = s * (1.f / 128.f);
                float var  = fmaxf(s2 * (1.f / 128.f) - mean * mean, 0.f);
                float inv  = rsqrtf(var + 1e-5f);
                #pragma unroll
                for (int nt = 0; nt < 2; ++nt) {
                    int f = wave * 32 + nt * 16 + lhi * 4;
                    float4 gq  = *(const float4*)&sm.par[128 + f];
                    float4 beq = *(const float4*)&sm.par[256 + f];
                    ushort4 pk;
                    #pragma unroll
                    for (int r = 0; r < 4; ++r) {
                        float v = (acc[nt][mt][r] - mean) * inv * ((const float*)&gq)[r] + ((const float*)&beq)[r];
                        ((unsigned short*)&pk)[r] = f2b(fmaxf(v, 0.f));
                    }
                    *(ushort4*)swzp(sm.u.p.y, edge, 256, 2 * f) = pk;
                }
            }
        }
        lbar();   // (3) y complete

        // ---------------- GRU: weights read ONCE; both edge-groups accumulated ----------------
        {
            f32x4 gr[2][2], gz[2][2], gn[2][2], gh[2][2];
            #pragma unroll
            for (int nt = 0; nt < 2; ++nt)
                #pragma unroll
                for (int mt = 0; mt < 2; ++mt) {
                    gr[nt][mt] = (f32x4){0.f,0.f,0.f,0.f}; gz[nt][mt] = (f32x4){0.f,0.f,0.f,0.f};
                    gn[nt][mt] = (f32x4){0.f,0.f,0.f,0.f}; gh[nt][mt] = (f32x4){0.f,0.f,0.f,0.f};
                }
            const unsigned short* pi = Wihbf + (size_t)(wave * 32 + llo) * 128 + lhi * 8;
            const unsigned short* pw = Whhbf + (size_t)(wave * 32 + llo) * 128 + lhi * 8;
            #pragma unroll
            for (int ks = 0; ks < 4; ++ks) {
                bf16x8 wfr[2], wfz[2], wfn[2], vfr[2], vfz[2], vfn[2];
                #pragma unroll
                for (int nt = 0; nt < 2; ++nt) {
                    const size_t ro = (size_t)nt * 16 * 128 + ks * 32;
                    wfr[nt] = *(const bf16x8*)(pi + ro);
                    wfz[nt] = *(const bf16x8*)(pi + 128 * 128 + ro);
                    wfn[nt] = *(const bf16x8*)(pi + 256 * 128 + ro);
                    vfr[nt] = *(const bf16x8*)(pw + ro);
                    vfz[nt] = *(const bf16x8*)(pw + 128 * 128 + ro);
                    vfn[nt] = *(const bf16x8*)(pw + 256 * 128 + ro);
                }
                #pragma unroll
                for (int mt = 0; mt < 2; ++mt) {
                    bf16x8 ay = *(const bf16x8*)swzp(sm.u.p.y, mt * 16 + llo, 256, ks * 64 + lhi * 16);
                    bf16x8 ah = *(const bf16x8*)swzp(sm.hbf,  mt * 16 + llo, 256, ks * 64 + lhi * 16);
                    #pragma unroll
                    for (int nt = 0; nt < 2; ++nt) {
                        gr[nt][mt] = MFMA(wfr[nt], ay, gr[nt][mt]);
                        gr[nt][mt] = MFMA(vfr[nt], ah, gr[nt][mt]);
                        gz[nt][mt] = MFMA(wfz[nt], ay, gz[nt][mt]);
                        gz[nt][mt] = MFMA(vfz[nt], ah, gz[nt][mt]);
                        gn[nt][mt] = MFMA(wfn[nt], ay, gn[nt][mt]);
                        gh[nt][mt] = MFMA(vfn[nt], ah, gh[nt][mt]);
                    }
                }
            }
            // GRU epilogue: sigmoid/tanh, blend, hnew write + direct hout store
            #pragma unroll
            for (int nt = 0; nt < 2; ++nt) {
                int f = wave * 32 + nt * 16 + lhi * 4;
                float4 bi0 = *(const float4*)&sm.par[384 + f];
                float4 bi1 = *(const float4*)&sm.par[512 + f];
                float4 bi2 = *(const float4*)&sm.par[640 + f];
                float4 bh0 = *(const float4*)&sm.par[768 + f];
                float4 bh1 = *(const float4*)&sm.par[896 + f];
                float4 bh2 = *(const float4*)&sm.par[1024 + f];
                #pragma unroll
                for (int mt = 0; mt < 2; ++mt) {
                    int edge = mt * 16 + llo;
                    ushort4 hp = *(const ushort4*)swzp(sm.hbf, edge, 256, 2 * f);
                    ushort4 pk; float4 ho;
                    #pragma unroll
                    for (int r = 0; r < 4; ++r) {
                        float rr = sigm(gr[nt][mt][r] + ((const float*)&bi0)[r] + ((const float*)&bh0)[r]);
                        float zz = sigm(gz[nt][mt][r] + ((const float*)&bi1)[r] + ((const float*)&bh1)[r]);
                        float nn = tanh_fast(gn[nt][mt][r] + ((const float*)&bi2)[r]
                                             + rr * (gh[nt][mt][r] + ((const float*)&bh2)[r]));
                        float hv = b2f(((const unsigned short*)&hp)[r]);
                        float hnv = (1.f - zz) * nn + zz * hv;
                        ((unsigned short*)&pk)[r] = f2b(hnv);
                        ((float*)&ho)[r] = hnv;
                    }
                    *(ushort4*)swzp(sm.u.p.hnew, edge, 256, 2 * f) = pk;
                    size_t e = e0 + edge;   // 4-lane lhi group covers a 64B sector
                    *(float4*)(hout + e * 128 + f) = ho;
                }
            }
        }
        lbar();   // (4) hnew complete

        // ---------------- GEMM3: Wx rows [16w,16w+16) x all 32 edges; direct xout ----------------
        {
            f32x4 a3[2];
            a3[0] = (f32x4){0.f,0.f,0.f,0.f}; a3[1] = (f32x4){0.f,0.f,0.f,0.f};
            const unsigned short* px = Wxbf + (size_t)(wave * 16 + llo) * 128 + lhi * 8;
            #pragma unroll
            for (int ks = 0; ks < 4; ++ks) {
                bf16x8 wf = *(const bf16x8*)(px + ks * 32);
                #pragma unroll
                for (int mt = 0; mt < 2; ++mt) {
                    bf16x8 bh = *(const bf16x8*)swzp(sm.u.p.hnew, mt * 16 + llo, 256, ks * 64 + lhi * 16);
                    a3[mt] = MFMA(wf, bh, a3[mt]);
                }
            }
            int fx = wave * 16 + lhi * 4;
            float4 bq = *(const float4*)&sm.par[1152 + fx];
            #pragma unroll
            for (int mt = 0; mt < 2; ++mt) {
                int edge = mt * 16 + llo;
                float4 o;
                o.x = a3[mt][0] + bq.x; o.y = a3[mt][1] + bq.y;
                o.z = a3[mt][2] + bq.z; o.w = a3[mt][3] + bq.w;
                size_t e = e0 + edge;   // 4-lane lhi group covers a 64B sector
                *(float4*)(xout + e * 64 + fx) = o;
            }
        }
        lbar();   // (5) all LDS reads done -> next tile may overwrite
    }
}

extern "C" void kernel_launch(void* const* d_in, const int* in_sizes, int n_in,
                              void* d_out, int out_size, void* d_ws, size_t ws_size,
                              hipStream_t stream)
{
    const float* src   = (const float*)d_in[0];
    const float* dst   = (const float*)d_in[1];
    const float* eat   = (const float*)d_in[2];
    const float* hin   = (const float*)d_in[3];
    const float* u     = (const float*)d_in[4];
    const int*   bat   = (const int*)d_in[5];
    const float* wind  = (const float*)d_in[6];
    const float* Ww    = (const float*)d_in[7];
    const float* bw    = (const float*)d_in[8];
    const float* gw    = (const float*)d_in[9];
    const float* betaw = (const float*)d_in[10];
    const float* W1    = (const float*)d_in[11];
    const float* b1    = (const float*)d_in[12];
    const float* g1    = (const float*)d_in[13];
    const float* beta1 = (const float*)d_in[14];
    const float* Wih   = (const float*)d_in[15];
    const float* Whh   = (const float*)d_in[16];
    const float* bih   = (const float*)d_in[17];
    const float* bhh   = (const float*)d_in[18];
    const float* Wx    = (const float*)d_in[19];
    const float* bx    = (const float*)d_in[20];

    unsigned short* wbuf = (unsigned short*)d_ws;   // 155648 bf16 = 304 KB
    wconv_kernel<<<608, 256, 0, stream>>>(W1, Wih, Whh, Wx, wbuf);

    float* xout = (float*)d_out;
    float* hout = xout + (size_t)E_TOTAL * 64;
    edge_model_kernel<<<NBLOCKS, 256, 0, stream>>>(
        src, dst, eat, hin, u, bat, wind, Ww, bw, gw, betaw,
        b1, g1, beta1, bih, bhh, bx,
        wbuf, wbuf + 49152, wbuf + 98304, wbuf + 147456,
        xout, hout);
}

// Round 11
// 828.820 us; speedup vs baseline: 4.3361x; 1.3447x over previous
//
#include <hip/hip_runtime.h>
#include <hip/hip_bf16.h>

#define E_TOTAL 500000
#define NB2 7813    // ceil(500000/64)
#define NB3 15625   // 500000/32, exact

typedef __attribute__((ext_vector_type(8))) short bf16x8;
typedef __attribute__((ext_vector_type(4))) float f32x4;

// D = A*B + C ; A rows -> C rows (features), B cols -> C cols (edges)
#define MFMA(a, b, c) __builtin_amdgcn_mfma_f32_16x16x32_bf16((a), (b), (c), 0, 0, 0)

// Barrier with LDS-only drain: global loads/stores stay in flight.
__device__ __forceinline__ void lbar() {
    asm volatile("s_waitcnt lgkmcnt(0)" ::: "memory");
    __builtin_amdgcn_s_barrier();
}
// pack two f32 -> two bf16 (round-half-up) in ~3 VALU ops via v_perm
__device__ __forceinline__ unsigned int pack2(float x, float y) {
    unsigned int xb = __builtin_bit_cast(unsigned int, x) + 0x8000u;
    unsigned int yb = __builtin_bit_cast(unsigned int, y) + 0x8000u;
    return __builtin_amdgcn_perm(yb, xb, 0x07060302u);
}
__device__ __forceinline__ float sigm(float x) { return 1.f / (1.f + __expf(-x)); }
__device__ __forceinline__ float tanh_fast(float x) {
    float t = __expf(-2.f * x);
    return (1.f - t) / (1.f + t);
}
// XOR-swizzled LDS address (T2)
__device__ __forceinline__ char* swzp(void* base, int row, int rowBytes, int colByte) {
    return (char*)base + row * rowBytes + (colByte ^ ((row & 7) << 4));
}

// ---------------- K1: weights f32 -> bf16 ----------------
__global__ void wconv_kernel(const float* __restrict__ W1, const float* __restrict__ Wih,
                             const float* __restrict__ Whh, const float* __restrict__ Wx,
                             unsigned short* __restrict__ out) {
    int i = blockIdx.x * 256 + threadIdx.x;
    if (i >= 155648) return;
    float v;
    if      (i < 49152)  v = W1[i];
    else if (i < 98304)  v = Wih[i - 49152];
    else if (i < 147456) v = Whh[i - 98304];
    else                 v = Wx[i - 147456];
    unsigned int b = __builtin_bit_cast(unsigned int, v) + 0x8000u;
    out[i] = (unsigned short)(b >> 16);
}

// ---------------- K2: concat + winding MLP + GEMM1 + LN + ReLU -> y (bf16) ----------------
// 256 threads, 64-edge tile, exact grid. LDS 52.5 KB -> 3 blocks/CU.
struct SmemM {
    unsigned short x1[64][384];   // 49152, swizzled, stride 768B
    float lns[64][4];             // 1024
    float ln2[64][4];             // 1024
    float par[640];               // 2560: Ww(256) bw(128) gw(128) betaw(128)
};

__global__ __launch_bounds__(256) void mlp1_kernel(
    const float* __restrict__ src, const float* __restrict__ dst,
    const float* __restrict__ eat, const float* __restrict__ u,
    const int* __restrict__ batch, const float* __restrict__ winding,
    const float* __restrict__ Ww, const float* __restrict__ bw,
    const float* __restrict__ gw, const float* __restrict__ betaw,
    const float* __restrict__ b1, const float* __restrict__ g1,
    const float* __restrict__ beta1,
    const unsigned short* __restrict__ W1bf,
    unsigned short* __restrict__ ybf)
{
    __shared__ SmemM sm;
    const int tid  = threadIdx.x;
    const int wave = tid >> 6;        // 0..3; owns features [32w, 32w+32)
    const int lane = tid & 63;
    const int lhi  = lane >> 4;
    const int llo  = lane & 15;
    const size_t e0 = (size_t)blockIdx.x * 64;

    // stage winding params (2.5 KB)
    for (int i = tid; i < 640; i += 256) {
        float v;
        if      (i < 256) v = Ww[i];
        else if (i < 384) v = bw[i - 256];
        else if (i < 512) v = gw[i - 384];
        else              v = betaw[i - 512];
        sm.par[i] = v;
    }
    lbar();

    // ---- stage x1 (src|dst|eat|u[batch]) swizzled, v_perm packing ----
    #pragma unroll
    for (int it = 0; it < 4; ++it) {
        int q   = it * 256 + tid;            // 1024 float4-quads
        int row = q >> 4;
        int c4  = (q & 15) << 2;
        size_t e = e0 + row; if (e >= E_TOTAL) e = E_TOTAL - 1;
        float4 a = *(const float4*)(src + e * 64 + c4);
        float4 b = *(const float4*)(dst + e * 64 + c4);
        float4 c = *(const float4*)(eat + e * 64 + c4);
        int bi   = batch[e];
        float4 d = *(const float4*)(u + (size_t)bi * 64 + c4);
        uint2 pa = make_uint2(pack2(a.x, a.y), pack2(a.z, a.w));
        uint2 pb = make_uint2(pack2(b.x, b.y), pack2(b.z, b.w));
        uint2 pc = make_uint2(pack2(c.x, c.y), pack2(c.z, c.w));
        uint2 pd = make_uint2(pack2(d.x, d.y), pack2(d.z, d.w));
        *(uint2*)swzp(sm.x1, row, 768, 2 * c4)       = pa;
        *(uint2*)swzp(sm.x1, row, 768, 128 + 2 * c4) = pb;
        *(uint2*)swzp(sm.x1, row, 768, 256 + 2 * c4) = pc;
        *(uint2*)swzp(sm.x1, row, 768, 384 + 2 * c4) = pd;
    }
    {   // winding MLP: Linear(2->128)+LN+ReLU, 4 threads/row
        int row = tid >> 2;
        int seg = tid & 3;
        size_t e = e0 + row; if (e >= E_TOTAL) e = E_TOTAL - 1;
        float wi0 = winding[e * 2], wi1 = winding[e * 2 + 1];
        float vals[32]; float s = 0.f, s2 = 0.f;
        #pragma unroll
        for (int j = 0; j < 32; ++j) {
            int jj = seg * 32 + j;
            float v = fmaf(wi0, sm.par[2 * jj], fmaf(wi1, sm.par[2 * jj + 1], sm.par[256 + jj]));
            vals[j] = v; s += v; s2 += v * v;
        }
        s  += __shfl_xor(s, 1);  s  += __shfl_xor(s, 2);
        s2 += __shfl_xor(s2, 1); s2 += __shfl_xor(s2, 2);
        float mean = s * (1.f / 128.f);
        float var  = fmaxf(s2 * (1.f / 128.f) - mean * mean, 0.f);
        float inv  = rsqrtf(var + 1e-5f);
        #pragma unroll
        for (int j4 = 0; j4 < 8; ++j4) {
            float v0, v1, v2, v3;
            {
                int jj = seg * 32 + j4 * 4;
                v0 = fmaxf((vals[j4*4+0] - mean) * inv * sm.par[384 + jj]     + sm.par[512 + jj],     0.f);
                v1 = fmaxf((vals[j4*4+1] - mean) * inv * sm.par[384 + jj + 1] + sm.par[512 + jj + 1], 0.f);
                v2 = fmaxf((vals[j4*4+2] - mean) * inv * sm.par[384 + jj + 2] + sm.par[512 + jj + 2], 0.f);
                v3 = fmaxf((vals[j4*4+3] - mean) * inv * sm.par[384 + jj + 3] + sm.par[512 + jj + 3], 0.f);
            }
            uint2 pk = make_uint2(pack2(v0, v1), pack2(v2, v3));
            *(uint2*)swzp(sm.x1, row, 768, 512 + seg * 64 + j4 * 8) = pk;
        }
    }
    lbar();   // staging complete

    // ---- GEMM1 (transposed): acc[nt][mt] ----
    f32x4 acc[2][4];
    #pragma unroll
    for (int nt = 0; nt < 2; ++nt)
        #pragma unroll
        for (int mt = 0; mt < 4; ++mt) acc[nt][mt] = (f32x4){0.f, 0.f, 0.f, 0.f};
    {
        const unsigned short* wp = W1bf + (size_t)(wave * 32 + llo) * 384 + lhi * 8;
        #pragma unroll
        for (int ks = 0; ks < 12; ++ks) {
            bf16x8 wf0 = *(const bf16x8*)(wp + ks * 32);
            bf16x8 wf1 = *(const bf16x8*)(wp + 16 * 384 + ks * 32);
            #pragma unroll
            for (int mt = 0; mt < 4; ++mt) {
                bf16x8 xf = *(const bf16x8*)swzp(sm.x1, mt * 16 + llo, 768, ks * 64 + lhi * 16);
                acc[0][mt] = MFMA(wf0, xf, acc[0][mt]);
                acc[1][mt] = MFMA(wf1, xf, acc[1][mt]);
            }
        }
    }
    {   // bias + per-wave LN partials
        float4 b1q0 = *(const float4*)&b1[wave * 32 + lhi * 4];
        float4 b1q1 = *(const float4*)&b1[wave * 32 + 16 + lhi * 4];
        #pragma unroll
        for (int mt = 0; mt < 4; ++mt) {
            float s = 0.f, s2 = 0.f;
            #pragma unroll
            for (int r = 0; r < 4; ++r) {
                float v0 = acc[0][mt][r] + ((const float*)&b1q0)[r];
                float v1 = acc[1][mt][r] + ((const float*)&b1q1)[r];
                acc[0][mt][r] = v0; acc[1][mt][r] = v1;
                s += v0 + v1; s2 += v0 * v0 + v1 * v1;
            }
            s  += __shfl_xor(s, 16);  s  += __shfl_xor(s, 32);
            s2 += __shfl_xor(s2, 16); s2 += __shfl_xor(s2, 32);
            if (lane < 16) { sm.lns[mt * 16 + llo][wave] = s; sm.ln2[mt * 16 + llo][wave] = s2; }
        }
    }
    lbar();   // partials ready

    {   // LN apply + ReLU + direct global y store (bf16)
        float4 g1q0  = *(const float4*)&g1[wave * 32 + lhi * 4];
        float4 g1q1  = *(const float4*)&g1[wave * 32 + 16 + lhi * 4];
        float4 be1q0 = *(const float4*)&beta1[wave * 32 + lhi * 4];
        float4 be1q1 = *(const float4*)&beta1[wave * 32 + 16 + lhi * 4];
        #pragma unroll
        for (int mt = 0; mt < 4; ++mt) {
            int edge = mt * 16 + llo;
            size_t e = e0 + edge;
            float4 sa = *(const float4*)&sm.lns[edge][0];
            float4 ta = *(const float4*)&sm.ln2[edge][0];
            float s  = sa.x + sa.y + sa.z + sa.w;
            float s2 = ta.x + ta.y + ta.z + ta.w;
            float mean = s * (1.f / 128.f);
            float var  = fmaxf(s2 * (1.f / 128.f) - mean * mean, 0.f);
            float inv  = rsqrtf(var + 1e-5f);
            if (e < E_TOTAL) {
                #pragma unroll
                for (int nt = 0; nt < 2; ++nt) {
                    const float4& gq  = nt ? g1q1 : g1q0;
                    const float4& beq = nt ? be1q1 : be1q0;
                    float v0 = fmaxf((acc[nt][mt][0] - mean) * inv * gq.x + beq.x, 0.f);
                    float v1 = fmaxf((acc[nt][mt][1] - mean) * inv * gq.y + beq.y, 0.f);
                    float v2 = fmaxf((acc[nt][mt][2] - mean) * inv * gq.z + beq.z, 0.f);
                    float v3 = fmaxf((acc[nt][mt][3] - mean) * inv * gq.w + beq.w, 0.f);
                    uint2 pk = make_uint2(pack2(v0, v1), pack2(v2, v3));
                    int f = wave * 32 + nt * 16 + lhi * 4;
                    *(uint2*)(ybf + e * 128 + f) = pk;
                }
            }
        }
    }
}

// ---------------- K3: GRU + blend + GEMM3 ----------------
// 256 threads, 32-edge tile, exact grid. No staging phase; y/h fragments from global.
__global__ __launch_bounds__(256) void gru_kernel(
    const unsigned short* __restrict__ ybf, const float* __restrict__ hin,
    const float* __restrict__ bih, const float* __restrict__ bhh,
    const float* __restrict__ bx,
    const unsigned short* __restrict__ Wihbf, const unsigned short* __restrict__ Whhbf,
    const unsigned short* __restrict__ Wxbf,
    float* __restrict__ xout, float* __restrict__ hout)
{
    __shared__ unsigned short hnew[32][128];   // swizzled, stride 256B
    const int tid  = threadIdx.x;
    const int wave = tid >> 6;        // 0..3; owns features [32w, 32w+32)
    const int lane = tid & 63;
    const int lhi  = lane >> 4;
    const int llo  = lane & 15;
    const size_t e0 = (size_t)blockIdx.x * 32;

    // accumulators [mt][nt]: gates r, z, n(input), n(hidden)
    f32x4 gr[2][2], gz[2][2], gn[2][2], gh[2][2];
    #pragma unroll
    for (int mt = 0; mt < 2; ++mt)
        #pragma unroll
        for (int nt = 0; nt < 2; ++nt) {
            gr[mt][nt] = (f32x4){0.f,0.f,0.f,0.f}; gz[mt][nt] = (f32x4){0.f,0.f,0.f,0.f};
            gn[mt][nt] = (f32x4){0.f,0.f,0.f,0.f}; gh[mt][nt] = (f32x4){0.f,0.f,0.f,0.f};
        }
    {
        const unsigned short* pi = Wihbf + (size_t)(wave * 32 + llo) * 128 + lhi * 8;
        const unsigned short* pw = Whhbf + (size_t)(wave * 32 + llo) * 128 + lhi * 8;
        #pragma unroll
        for (int ks = 0; ks < 4; ++ks) {
            bf16x8 wr[2], wz[2], wn[2], vr[2], vz[2], vn[2];
            #pragma unroll
            for (int nt = 0; nt < 2; ++nt) {
                const size_t ro = (size_t)nt * 16 * 128 + ks * 32;
                wr[nt] = *(const bf16x8*)(pi + ro);
                wz[nt] = *(const bf16x8*)(pi + 128 * 128 + ro);
                wn[nt] = *(const bf16x8*)(pi + 256 * 128 + ro);
                vr[nt] = *(const bf16x8*)(pw + ro);
                vz[nt] = *(const bf16x8*)(pw + 128 * 128 + ro);
                vn[nt] = *(const bf16x8*)(pw + 256 * 128 + ro);
            }
            #pragma unroll
            for (int mt = 0; mt < 2; ++mt) {
                size_t e = e0 + mt * 16 + llo;
                bf16x8 ay = *(const bf16x8*)(ybf + e * 128 + ks * 32 + lhi * 8);
                float4 h0 = *(const float4*)(hin + e * 128 + ks * 32 + lhi * 8);
                float4 h1 = *(const float4*)(hin + e * 128 + ks * 32 + lhi * 8 + 4);
                uint4 up;
                up.x = pack2(h0.x, h0.y); up.y = pack2(h0.z, h0.w);
                up.z = pack2(h1.x, h1.y); up.w = pack2(h1.z, h1.w);
                bf16x8 ah = __builtin_bit_cast(bf16x8, up);
                #pragma unroll
                for (int nt = 0; nt < 2; ++nt) {
                    gr[mt][nt] = MFMA(wr[nt], ay, gr[mt][nt]);
                    gr[mt][nt] = MFMA(vr[nt], ah, gr[mt][nt]);
                    gz[mt][nt] = MFMA(wz[nt], ay, gz[mt][nt]);
                    gz[mt][nt] = MFMA(vz[nt], ah, gz[mt][nt]);
                    gn[mt][nt] = MFMA(wn[nt], ay, gn[mt][nt]);
                    gh[mt][nt] = MFMA(vn[nt], ah, gh[mt][nt]);
                }
            }
        }
    }
    // epilogue: gates + blend (exact f32 h) + hout store + hnew -> LDS
    #pragma unroll
    for (int nt = 0; nt < 2; ++nt) {
        int f = wave * 32 + nt * 16 + lhi * 4;
        float4 bi0 = *(const float4*)&bih[f];
        float4 bi1 = *(const float4*)&bih[128 + f];
        float4 bi2 = *(const float4*)&bih[256 + f];
        float4 bh0 = *(const float4*)&bhh[f];
        float4 bh1 = *(const float4*)&bhh[128 + f];
        float4 bh2 = *(const float4*)&bhh[256 + f];
        #pragma unroll
        for (int mt = 0; mt < 2; ++mt) {
            size_t e = e0 + mt * 16 + llo;
            float4 hv = *(const float4*)(hin + e * 128 + f);
            float4 ho;
            #pragma unroll
            for (int r = 0; r < 4; ++r) {
                float rr = sigm(gr[mt][nt][r] + ((const float*)&bi0)[r] + ((const float*)&bh0)[r]);
                float zz = sigm(gz[mt][nt][r] + ((const float*)&bi1)[r] + ((const float*)&bh1)[r]);
                float nn = tanh_fast(gn[mt][nt][r] + ((const float*)&bi2)[r]
                                     + rr * (gh[mt][nt][r] + ((const float*)&bh2)[r]));
                ((float*)&ho)[r] = (1.f - zz) * nn + zz * ((const float*)&hv)[r];
            }
            *(float4*)(hout + e * 128 + f) = ho;
            uint2 pk = make_uint2(pack2(ho.x, ho.y), pack2(ho.z, ho.w));
            *(uint2*)swzp(hnew, mt * 16 + llo, 256, 2 * f) = pk;
        }
    }
    lbar();   // hnew complete

    // GEMM3: Wx rows [16w,16w+16) x 32 edges; direct xout stores
    {
        f32x4 a3[2];
        a3[0] = (f32x4){0.f,0.f,0.f,0.f}; a3[1] = (f32x4){0.f,0.f,0.f,0.f};
        const unsigned short* px = Wxbf + (size_t)(wave * 16 + llo) * 128 + lhi * 8;
        #pragma unroll
        for (int ks = 0; ks < 4; ++ks) {
            bf16x8 wf = *(const bf16x8*)(px + ks * 32);
            #pragma unroll
            for (int mt = 0; mt < 2; ++mt) {
                bf16x8 bh = *(const bf16x8*)swzp(hnew, mt * 16 + llo, 256, ks * 64 + lhi * 16);
                a3[mt] = MFMA(wf, bh, a3[mt]);
            }
        }
        int fx = wave * 16 + lhi * 4;
        float4 bq = *(const float4*)&bx[fx];
        #pragma unroll
        for (int mt = 0; mt < 2; ++mt) {
            size_t e = e0 + mt * 16 + llo;
            float4 o;
            o.x = a3[mt][0] + bq.x; o.y = a3[mt][1] + bq.y;
            o.z = a3[mt][2] + bq.z; o.w = a3[mt][3] + bq.w;
            *(float4*)(xout + e * 64 + fx) = o;
        }
    }
}

extern "C" void kernel_launch(void* const* d_in, const int* in_sizes, int n_in,
                              void* d_out, int out_size, void* d_ws, size_t ws_size,
                              hipStream_t stream)
{
    const float* src   = (const float*)d_in[0];
    const float* dst   = (const float*)d_in[1];
    const float* eat   = (const float*)d_in[2];
    const float* hin   = (const float*)d_in[3];
    const float* u     = (const float*)d_in[4];
    const int*   bat   = (const int*)d_in[5];
    const float* wind  = (const float*)d_in[6];
    const float* Ww    = (const float*)d_in[7];
    const float* bw    = (const float*)d_in[8];
    const float* gw    = (const float*)d_in[9];
    const float* betaw = (const float*)d_in[10];
    const float* W1    = (const float*)d_in[11];
    const float* b1    = (const float*)d_in[12];
    const float* g1    = (const float*)d_in[13];
    const float* beta1 = (const float*)d_in[14];
    const float* Wih   = (const float*)d_in[15];
    const float* Whh   = (const float*)d_in[16];
    const float* bih   = (const float*)d_in[17];
    const float* bhh   = (const float*)d_in[18];
    const float* Wx    = (const float*)d_in[19];
    const float* bx    = (const float*)d_in[20];

    // workspace layout: y (E*128 bf16 = 128 MB) | weights bf16 (304 KB)
    unsigned short* ybf  = (unsigned short*)d_ws;
    unsigned short* wbuf = ybf + 64000000ull;

    wconv_kernel<<<608, 256, 0, stream>>>(W1, Wih, Whh, Wx, wbuf);

    float* xout = (float*)d_out;
    float* hout = xout + (size_t)E_TOTAL * 64;

    mlp1_kernel<<<NB2, 256, 0, stream>>>(
        src, dst, eat, u, bat, wind, Ww, bw, gw, betaw,
        b1, g1, beta1, wbuf, ybf);

    gru_kernel<<<NB3, 256, 0, stream>>>(
        ybf, hin, bih, bhh, bx,
        wbuf + 49152, wbuf + 98304, wbuf + 147456,
        xout, hout);
}

// Round 12
// 760.923 us; speedup vs baseline: 4.7230x; 1.0892x over previous
//
#include <hip/hip_runtime.h>
#include <hip/hip_bf16.h>

#define E_TOTAL 500000
#define NB2 7813    // ceil(500000/64)
#define NB3 7813    // ceil(500000/64)

typedef __attribute__((ext_vector_type(8))) short bf16x8;
typedef __attribute__((ext_vector_type(4))) float f32x4;

// D = A*B + C ; A rows -> C rows (features), B cols -> C cols (edges)
#define MFMA(a, b, c) __builtin_amdgcn_mfma_f32_16x16x32_bf16((a), (b), (c), 0, 0, 0)

// Barrier with LDS-only drain: global loads/stores stay in flight.
__device__ __forceinline__ void lbar() {
    asm volatile("s_waitcnt lgkmcnt(0)" ::: "memory");
    __builtin_amdgcn_s_barrier();
}
// pack two f32 -> two bf16 (round-half-up) in ~3 VALU ops via v_perm
__device__ __forceinline__ unsigned int pack2(float x, float y) {
    unsigned int xb = __builtin_bit_cast(unsigned int, x) + 0x8000u;
    unsigned int yb = __builtin_bit_cast(unsigned int, y) + 0x8000u;
    return __builtin_amdgcn_perm(yb, xb, 0x07060302u);
}
__device__ __forceinline__ float sigm(float x) { return 1.f / (1.f + __expf(-x)); }
__device__ __forceinline__ float tanh_fast(float x) {
    float t = __expf(-2.f * x);
    return (1.f - t) / (1.f + t);
}
// XOR-swizzled LDS address (T2)
__device__ __forceinline__ char* swzp(void* base, int row, int rowBytes, int colByte) {
    return (char*)base + row * rowBytes + (colByte ^ ((row & 7) << 4));
}

// ---------------- K1: weights f32 -> bf16 ----------------
__global__ void wconv_kernel(const float* __restrict__ W1, const float* __restrict__ Wih,
                             const float* __restrict__ Whh, const float* __restrict__ Wx,
                             unsigned short* __restrict__ out) {
    int i = blockIdx.x * 256 + threadIdx.x;
    if (i >= 155648) return;
    float v;
    if      (i < 49152)  v = W1[i];
    else if (i < 98304)  v = Wih[i - 49152];
    else if (i < 147456) v = Whh[i - 98304];
    else                 v = Wx[i - 147456];
    unsigned int b = __builtin_bit_cast(unsigned int, v) + 0x8000u;
    out[i] = (unsigned short)(b >> 16);
}

// ---------------- K2: concat + winding MLP + GEMM1 + LN + ReLU -> y (bf16) ----------------
struct SmemM {
    unsigned short x1[64][384];   // 49152, swizzled, stride 768B
    float lns[64][4];             // 1024
    float ln2[64][4];             // 1024
    float par[640];               // 2560: Ww(256) bw(128) gw(128) betaw(128)
};

__global__ __launch_bounds__(256) void mlp1_kernel(
    const float* __restrict__ src, const float* __restrict__ dst,
    const float* __restrict__ eat, const float* __restrict__ u,
    const int* __restrict__ batch, const float* __restrict__ winding,
    const float* __restrict__ Ww, const float* __restrict__ bw,
    const float* __restrict__ gw, const float* __restrict__ betaw,
    const float* __restrict__ b1, const float* __restrict__ g1,
    const float* __restrict__ beta1,
    const unsigned short* __restrict__ W1bf,
    unsigned short* __restrict__ ybf)
{
    __shared__ SmemM sm;
    const int tid  = threadIdx.x;
    const int wave = tid >> 6;        // 0..3; owns features [32w, 32w+32)
    const int lane = tid & 63;
    const int lhi  = lane >> 4;
    const int llo  = lane & 15;
    const size_t e0 = (size_t)blockIdx.x * 64;

    for (int i = tid; i < 640; i += 256) {
        float v;
        if      (i < 256) v = Ww[i];
        else if (i < 384) v = bw[i - 256];
        else if (i < 512) v = gw[i - 384];
        else              v = betaw[i - 512];
        sm.par[i] = v;
    }
    lbar();

    #pragma unroll
    for (int it = 0; it < 4; ++it) {
        int q   = it * 256 + tid;            // 1024 float4-quads
        int row = q >> 4;
        int c4  = (q & 15) << 2;
        size_t e = e0 + row; if (e >= E_TOTAL) e = E_TOTAL - 1;
        float4 a = *(const float4*)(src + e * 64 + c4);
        float4 b = *(const float4*)(dst + e * 64 + c4);
        float4 c = *(const float4*)(eat + e * 64 + c4);
        int bi   = batch[e];
        float4 d = *(const float4*)(u + (size_t)bi * 64 + c4);
        uint2 pa = make_uint2(pack2(a.x, a.y), pack2(a.z, a.w));
        uint2 pb = make_uint2(pack2(b.x, b.y), pack2(b.z, b.w));
        uint2 pc = make_uint2(pack2(c.x, c.y), pack2(c.z, c.w));
        uint2 pd = make_uint2(pack2(d.x, d.y), pack2(d.z, d.w));
        *(uint2*)swzp(sm.x1, row, 768, 2 * c4)       = pa;
        *(uint2*)swzp(sm.x1, row, 768, 128 + 2 * c4) = pb;
        *(uint2*)swzp(sm.x1, row, 768, 256 + 2 * c4) = pc;
        *(uint2*)swzp(sm.x1, row, 768, 384 + 2 * c4) = pd;
    }
    {   // winding MLP: Linear(2->128)+LN+ReLU, 4 threads/row
        int row = tid >> 2;
        int seg = tid & 3;
        size_t e = e0 + row; if (e >= E_TOTAL) e = E_TOTAL - 1;
        float wi0 = winding[e * 2], wi1 = winding[e * 2 + 1];
        float vals[32]; float s = 0.f, s2 = 0.f;
        #pragma unroll
        for (int j = 0; j < 32; ++j) {
            int jj = seg * 32 + j;
            float v = fmaf(wi0, sm.par[2 * jj], fmaf(wi1, sm.par[2 * jj + 1], sm.par[256 + jj]));
            vals[j] = v; s += v; s2 += v * v;
        }
        s  += __shfl_xor(s, 1);  s  += __shfl_xor(s, 2);
        s2 += __shfl_xor(s2, 1); s2 += __shfl_xor(s2, 2);
        float mean = s * (1.f / 128.f);
        float var  = fmaxf(s2 * (1.f / 128.f) - mean * mean, 0.f);
        float inv  = rsqrtf(var + 1e-5f);
        #pragma unroll
        for (int j4 = 0; j4 < 8; ++j4) {
            float v0, v1, v2, v3;
            {
                int jj = seg * 32 + j4 * 4;
                v0 = fmaxf((vals[j4*4+0] - mean) * inv * sm.par[384 + jj]     + sm.par[512 + jj],     0.f);
                v1 = fmaxf((vals[j4*4+1] - mean) * inv * sm.par[384 + jj + 1] + sm.par[512 + jj + 1], 0.f);
                v2 = fmaxf((vals[j4*4+2] - mean) * inv * sm.par[384 + jj + 2] + sm.par[512 + jj + 2], 0.f);
                v3 = fmaxf((vals[j4*4+3] - mean) * inv * sm.par[384 + jj + 3] + sm.par[512 + jj + 3], 0.f);
            }
            uint2 pk = make_uint2(pack2(v0, v1), pack2(v2, v3));
            *(uint2*)swzp(sm.x1, row, 768, 512 + seg * 64 + j4 * 8) = pk;
        }
    }
    lbar();   // staging complete

    f32x4 acc[2][4];
    #pragma unroll
    for (int nt = 0; nt < 2; ++nt)
        #pragma unroll
        for (int mt = 0; mt < 4; ++mt) acc[nt][mt] = (f32x4){0.f, 0.f, 0.f, 0.f};
    {
        const unsigned short* wp = W1bf + (size_t)(wave * 32 + llo) * 384 + lhi * 8;
        #pragma unroll
        for (int ks = 0; ks < 12; ++ks) {
            bf16x8 wf0 = *(const bf16x8*)(wp + ks * 32);
            bf16x8 wf1 = *(const bf16x8*)(wp + 16 * 384 + ks * 32);
            #pragma unroll
            for (int mt = 0; mt < 4; ++mt) {
                bf16x8 xf = *(const bf16x8*)swzp(sm.x1, mt * 16 + llo, 768, ks * 64 + lhi * 16);
                acc[0][mt] = MFMA(wf0, xf, acc[0][mt]);
                acc[1][mt] = MFMA(wf1, xf, acc[1][mt]);
            }
        }
    }
    {   // bias + per-wave LN partials
        float4 b1q0 = *(const float4*)&b1[wave * 32 + lhi * 4];
        float4 b1q1 = *(const float4*)&b1[wave * 32 + 16 + lhi * 4];
        #pragma unroll
        for (int mt = 0; mt < 4; ++mt) {
            float s = 0.f, s2 = 0.f;
            #pragma unroll
            for (int r = 0; r < 4; ++r) {
                float v0 = acc[0][mt][r] + ((const float*)&b1q0)[r];
                float v1 = acc[1][mt][r] + ((const float*)&b1q1)[r];
                acc[0][mt][r] = v0; acc[1][mt][r] = v1;
                s += v0 + v1; s2 += v0 * v0 + v1 * v1;
            }
            s  += __shfl_xor(s, 16);  s  += __shfl_xor(s, 32);
            s2 += __shfl_xor(s2, 16); s2 += __shfl_xor(s2, 32);
            if (lane < 16) { sm.lns[mt * 16 + llo][wave] = s; sm.ln2[mt * 16 + llo][wave] = s2; }
        }
    }
    lbar();   // partials ready

    {   // LN apply + ReLU + direct global y store (bf16)
        float4 g1q0  = *(const float4*)&g1[wave * 32 + lhi * 4];
        float4 g1q1  = *(const float4*)&g1[wave * 32 + 16 + lhi * 4];
        float4 be1q0 = *(const float4*)&beta1[wave * 32 + lhi * 4];
        float4 be1q1 = *(const float4*)&beta1[wave * 32 + 16 + lhi * 4];
        #pragma unroll
        for (int mt = 0; mt < 4; ++mt) {
            int edge = mt * 16 + llo;
            size_t e = e0 + edge;
            float4 sa = *(const float4*)&sm.lns[edge][0];
            float4 ta = *(const float4*)&sm.ln2[edge][0];
            float s  = sa.x + sa.y + sa.z + sa.w;
            float s2 = ta.x + ta.y + ta.z + ta.w;
            float mean = s * (1.f / 128.f);
            float var  = fmaxf(s2 * (1.f / 128.f) - mean * mean, 0.f);
            float inv  = rsqrtf(var + 1e-5f);
            if (e < E_TOTAL) {
                #pragma unroll
                for (int nt = 0; nt < 2; ++nt) {
                    const float4& gq  = nt ? g1q1 : g1q0;
                    const float4& beq = nt ? be1q1 : be1q0;
                    float v0 = fmaxf((acc[nt][mt][0] - mean) * inv * gq.x + beq.x, 0.f);
                    float v1 = fmaxf((acc[nt][mt][1] - mean) * inv * gq.y + beq.y, 0.f);
                    float v2 = fmaxf((acc[nt][mt][2] - mean) * inv * gq.z + beq.z, 0.f);
                    float v3 = fmaxf((acc[nt][mt][3] - mean) * inv * gq.w + beq.w, 0.f);
                    uint2 pk = make_uint2(pack2(v0, v1), pack2(v2, v3));
                    int f = wave * 32 + nt * 16 + lhi * 4;
                    *(uint2*)(ybf + e * 128 + f) = pk;
                }
            }
        }
    }
}

// ---------------- K3: GRU + blend + GEMM3 (64-edge tile, LDS-staged activations) ----------------
struct SmemG {
    union {
        unsigned short y[64][128];      // staged y; dead after GRU MFMA loop
        unsigned short hnew[64][128];   // aliases y after barrier
    } a;                                // 16384
    unsigned short h[64][128];          // staged h (bf16); 16384
};

__global__ __launch_bounds__(256) void gru_kernel(
    const unsigned short* __restrict__ ybf, const float* __restrict__ hin,
    const float* __restrict__ bih, const float* __restrict__ bhh,
    const float* __restrict__ bx,
    const unsigned short* __restrict__ Wihbf, const unsigned short* __restrict__ Whhbf,
    const unsigned short* __restrict__ Wxbf,
    float* __restrict__ xout, float* __restrict__ hout)
{
    __shared__ SmemG sm;
    const int tid  = threadIdx.x;
    const int wave = tid >> 6;        // 0..3; owns features [32w, 32w+32)
    const int lane = tid & 63;
    const int lhi  = lane >> 4;
    const int llo  = lane & 15;
    const size_t e0 = (size_t)blockIdx.x * 64;

    // ---- batch-stage y (bf16 copy) and h (f32 -> bf16 pack), swizzled ----
    #pragma unroll
    for (int it = 0; it < 4; ++it) {
        int q   = it * 256 + tid;            // 1024 16B-chunks
        int row = q >> 4;
        int c   = (q & 15) * 8;              // element offset
        size_t e = e0 + row; if (e >= E_TOTAL) e = E_TOTAL - 1;
        uint4 v = *(const uint4*)(ybf + e * 128 + c);
        *(uint4*)swzp(sm.a.y, row, 256, 2 * c) = v;
    }
    #pragma unroll
    for (int it = 0; it < 8; ++it) {
        int q   = it * 256 + tid;            // 2048 float4-quads
        int row = q >> 5;
        int c4  = (q & 31) << 2;
        size_t e = e0 + row; if (e >= E_TOTAL) e = E_TOTAL - 1;
        float4 v = *(const float4*)(hin + e * 128 + c4);
        uint2 pk = make_uint2(pack2(v.x, v.y), pack2(v.z, v.w));
        *(uint2*)swzp(sm.h, row, 256, 2 * c4) = pk;
    }
    lbar();   // (1) staging complete

    // ---- GRU gates: acc[mt=4][nt=2] per gate; weights streamed from L2 once ----
    f32x4 gr[4][2], gz[4][2], gn[4][2], gh[4][2];
    #pragma unroll
    for (int mt = 0; mt < 4; ++mt)
        #pragma unroll
        for (int nt = 0; nt < 2; ++nt) {
            gr[mt][nt] = (f32x4){0.f,0.f,0.f,0.f}; gz[mt][nt] = (f32x4){0.f,0.f,0.f,0.f};
            gn[mt][nt] = (f32x4){0.f,0.f,0.f,0.f}; gh[mt][nt] = (f32x4){0.f,0.f,0.f,0.f};
        }
    {
        const unsigned short* pi = Wihbf + (size_t)(wave * 32 + llo) * 128 + lhi * 8;
        const unsigned short* pw = Whhbf + (size_t)(wave * 32 + llo) * 128 + lhi * 8;
        #pragma unroll
        for (int ks = 0; ks < 4; ++ks) {
            bf16x8 wr[2], wz[2], wn[2], vr[2], vz[2], vn[2];
            #pragma unroll
            for (int nt = 0; nt < 2; ++nt) {
                const size_t ro = (size_t)nt * 16 * 128 + ks * 32;
                wr[nt] = *(const bf16x8*)(pi + ro);
                wz[nt] = *(const bf16x8*)(pi + 128 * 128 + ro);
                wn[nt] = *(const bf16x8*)(pi + 256 * 128 + ro);
                vr[nt] = *(const bf16x8*)(pw + ro);
                vz[nt] = *(const bf16x8*)(pw + 128 * 128 + ro);
                vn[nt] = *(const bf16x8*)(pw + 256 * 128 + ro);
            }
            #pragma unroll
            for (int mt = 0; mt < 4; ++mt) {
                bf16x8 ay = *(const bf16x8*)swzp(sm.a.y, mt * 16 + llo, 256, ks * 64 + lhi * 16);
                bf16x8 ah = *(const bf16x8*)swzp(sm.h,   mt * 16 + llo, 256, ks * 64 + lhi * 16);
                #pragma unroll
                for (int nt = 0; nt < 2; ++nt) {
                    gr[mt][nt] = MFMA(wr[nt], ay, gr[mt][nt]);
                    gr[mt][nt] = MFMA(vr[nt], ah, gr[mt][nt]);
                    gz[mt][nt] = MFMA(wz[nt], ay, gz[mt][nt]);
                    gz[mt][nt] = MFMA(vz[nt], ah, gz[mt][nt]);
                    gn[mt][nt] = MFMA(wn[nt], ay, gn[mt][nt]);
                    gh[mt][nt] = MFMA(vn[nt], ah, gh[mt][nt]);
                }
            }
        }
    }
    lbar();   // (2) y reads done -> hnew may alias y

    // ---- epilogue: gates + blend (exact f32 h from L2-hot global) + hout + hnew->LDS ----
    #pragma unroll
    for (int nt = 0; nt < 2; ++nt) {
        int f = wave * 32 + nt * 16 + lhi * 4;
        float4 bi0 = *(const float4*)&bih[f];
        float4 bi1 = *(const float4*)&bih[128 + f];
        float4 bi2 = *(const float4*)&bih[256 + f];
        float4 bh0 = *(const float4*)&bhh[f];
        float4 bh1 = *(const float4*)&bhh[128 + f];
        float4 bh2 = *(const float4*)&bhh[256 + f];
        #pragma unroll
        for (int mt = 0; mt < 4; ++mt) {
            size_t e = e0 + mt * 16 + llo;
            size_t ec = e < E_TOTAL ? e : E_TOTAL - 1;
            float4 hv = *(const float4*)(hin + ec * 128 + f);
            float4 ho;
            #pragma unroll
            for (int r = 0; r < 4; ++r) {
                float rr = sigm(gr[mt][nt][r] + ((const float*)&bi0)[r] + ((const float*)&bh0)[r]);
                float zz = sigm(gz[mt][nt][r] + ((const float*)&bi1)[r] + ((const float*)&bh1)[r]);
                float nn = tanh_fast(gn[mt][nt][r] + ((const float*)&bi2)[r]
                                     + rr * (gh[mt][nt][r] + ((const float*)&bh2)[r]));
                ((float*)&ho)[r] = (1.f - zz) * nn + zz * ((const float*)&hv)[r];
            }
            if (e < E_TOTAL) *(float4*)(hout + e * 128 + f) = ho;
            uint2 pk = make_uint2(pack2(ho.x, ho.y), pack2(ho.z, ho.w));
            *(uint2*)swzp(sm.a.hnew, mt * 16 + llo, 256, 2 * f) = pk;
        }
    }
    lbar();   // (3) hnew complete

    // ---- GEMM3: Wx rows [16w,16w+16) x 64 edges; direct xout stores ----
    {
        f32x4 a3[4];
        #pragma unroll
        for (int mt = 0; mt < 4; ++mt) a3[mt] = (f32x4){0.f,0.f,0.f,0.f};
        const unsigned short* px = Wxbf + (size_t)(wave * 16 + llo) * 128 + lhi * 8;
        #pragma unroll
        for (int ks = 0; ks < 4; ++ks) {
            bf16x8 wf = *(const bf16x8*)(px + ks * 32);
            #pragma unroll
            for (int mt = 0; mt < 4; ++mt) {
                bf16x8 bh = *(const bf16x8*)swzp(sm.a.hnew, mt * 16 + llo, 256, ks * 64 + lhi * 16);
                a3[mt] = MFMA(wf, bh, a3[mt]);
            }
        }
        int fx = wave * 16 + lhi * 4;
        float4 bq = *(const float4*)&bx[fx];
        #pragma unroll
        for (int mt = 0; mt < 4; ++mt) {
            size_t e = e0 + mt * 16 + llo;
            float4 o;
            o.x = a3[mt][0] + bq.x; o.y = a3[mt][1] + bq.y;
            o.z = a3[mt][2] + bq.z; o.w = a3[mt][3] + bq.w;
            if (e < E_TOTAL) *(float4*)(xout + e * 64 + fx) = o;
        }
    }
}

extern "C" void kernel_launch(void* const* d_in, const int* in_sizes, int n_in,
                              void* d_out, int out_size, void* d_ws, size_t ws_size,
                              hipStream_t stream)
{
    const float* src   = (const float*)d_in[0];
    const float* dst   = (const float*)d_in[1];
    const float* eat   = (const float*)d_in[2];
    const float* hin   = (const float*)d_in[3];
    const float* u     = (const float*)d_in[4];
    const int*   bat   = (const int*)d_in[5];
    const float* wind  = (const float*)d_in[6];
    const float* Ww    = (const float*)d_in[7];
    const float* bw    = (const float*)d_in[8];
    const float* gw    = (const float*)d_in[9];
    const float* betaw = (const float*)d_in[10];
    const float* W1    = (const float*)d_in[11];
    const float* b1    = (const float*)d_in[12];
    const float* g1    = (const float*)d_in[13];
    const float* beta1 = (const float*)d_in[14];
    const float* Wih   = (const float*)d_in[15];
    const float* Whh   = (const float*)d_in[16];
    const float* bih   = (const float*)d_in[17];
    const float* bhh   = (const float*)d_in[18];
    const float* Wx    = (const float*)d_in[19];
    const float* bx    = (const float*)d_in[20];

    // workspace layout: y (E*128 bf16 = 128 MB) | weights bf16 (304 KB)
    unsigned short* ybf  = (unsigned short*)d_ws;
    unsigned short* wbuf = ybf + 64000000ull;

    wconv_kernel<<<608, 256, 0, stream>>>(W1, Wih, Whh, Wx, wbuf);

    float* xout = (float*)d_out;
    float* hout = xout + (size_t)E_TOTAL * 64;

    mlp1_kernel<<<NB2, 256, 0, stream>>>(
        src, dst, eat, u, bat, wind, Ww, bw, gw, betaw,
        b1, g1, beta1, wbuf, ybf);

    gru_kernel<<<NB3, 256, 0, stream>>>(
        ybf, hin, bih, bhh, bx,
        wbuf + 49152, wbuf + 98304, wbuf + 147456,
        xout, hout);
}

// Round 13
// 760.371 us; speedup vs baseline: 4.7264x; 1.0007x over previous
//
#include <hip/hip_runtime.h>
#include <hip/hip_bf16.h>

#define E_TOTAL 500000
#define NB2 7813    // ceil(500000/64)
#define NB3 7813    // ceil(500000/64)

typedef __attribute__((ext_vector_type(8))) short bf16x8;
typedef __attribute__((ext_vector_type(4))) float f32x4;

// D = A*B + C ; A rows -> C rows (features), B cols -> C cols (edges)
#define MFMA(a, b, c) __builtin_amdgcn_mfma_f32_16x16x32_bf16((a), (b), (c), 0, 0, 0)

// Barrier with LDS-only drain: global loads/stores stay in flight.
__device__ __forceinline__ void lbar() {
    asm volatile("s_waitcnt lgkmcnt(0)" ::: "memory");
    __builtin_amdgcn_s_barrier();
}
// pack two f32 -> two bf16 (round-half-up) in ~3 VALU ops via v_perm
__device__ __forceinline__ unsigned int pack2(float x, float y) {
    unsigned int xb = __builtin_bit_cast(unsigned int, x) + 0x8000u;
    unsigned int yb = __builtin_bit_cast(unsigned int, y) + 0x8000u;
    return __builtin_amdgcn_perm(yb, xb, 0x07060302u);
}
__device__ __forceinline__ float sigm(float x) { return 1.f / (1.f + __expf(-x)); }
__device__ __forceinline__ float tanh_fast(float x) {
    float t = __expf(-2.f * x);
    return (1.f - t) / (1.f + t);
}
// XOR-swizzled LDS address (T2)
__device__ __forceinline__ char* swzp(void* base, int row, int rowBytes, int colByte) {
    return (char*)base + row * rowBytes + (colByte ^ ((row & 7) << 4));
}

// ---------------- K1: weights f32 -> bf16 ----------------
__global__ void wconv_kernel(const float* __restrict__ W1, const float* __restrict__ Wih,
                             const float* __restrict__ Whh, const float* __restrict__ Wx,
                             unsigned short* __restrict__ out) {
    int i = blockIdx.x * 256 + threadIdx.x;
    if (i >= 155648) return;
    float v;
    if      (i < 49152)  v = W1[i];
    else if (i < 98304)  v = Wih[i - 49152];
    else if (i < 147456) v = Whh[i - 98304];
    else                 v = Wx[i - 147456];
    unsigned int b = __builtin_bit_cast(unsigned int, v) + 0x8000u;
    out[i] = (unsigned short)(b >> 16);
}

// ---------------- K2: concat + winding MLP + GEMM1 + LN + ReLU -> y (bf16) ----------------
struct SmemM {
    unsigned short x1[64][384];   // 49152, swizzled, stride 768B
    float lns[64][4];             // 1024
    float ln2[64][4];             // 1024
    float par[640];               // 2560: Ww(256) bw(128) gw(128) betaw(128)
};

__global__ __launch_bounds__(256) void mlp1_kernel(
    const float* __restrict__ src, const float* __restrict__ dst,
    const float* __restrict__ eat, const float* __restrict__ u,
    const int* __restrict__ batch, const float* __restrict__ winding,
    const float* __restrict__ Ww, const float* __restrict__ bw,
    const float* __restrict__ gw, const float* __restrict__ betaw,
    const float* __restrict__ b1, const float* __restrict__ g1,
    const float* __restrict__ beta1,
    const unsigned short* __restrict__ W1bf,
    unsigned short* __restrict__ ybf)
{
    __shared__ SmemM sm;
    const int tid  = threadIdx.x;
    const int wave = tid >> 6;        // 0..3; owns features [32w, 32w+32)
    const int lane = tid & 63;
    const int lhi  = lane >> 4;
    const int llo  = lane & 15;
    const size_t e0 = (size_t)blockIdx.x * 64;

    for (int i = tid; i < 640; i += 256) {
        float v;
        if      (i < 256) v = Ww[i];
        else if (i < 384) v = bw[i - 256];
        else if (i < 512) v = gw[i - 384];
        else              v = betaw[i - 512];
        sm.par[i] = v;
    }
    lbar();

    #pragma unroll
    for (int it = 0; it < 4; ++it) {
        int q   = it * 256 + tid;            // 1024 float4-quads
        int row = q >> 4;
        int c4  = (q & 15) << 2;
        size_t e = e0 + row; if (e >= E_TOTAL) e = E_TOTAL - 1;
        float4 a = *(const float4*)(src + e * 64 + c4);
        float4 b = *(const float4*)(dst + e * 64 + c4);
        float4 c = *(const float4*)(eat + e * 64 + c4);
        int bi   = batch[e];
        float4 d = *(const float4*)(u + (size_t)bi * 64 + c4);
        uint2 pa = make_uint2(pack2(a.x, a.y), pack2(a.z, a.w));
        uint2 pb = make_uint2(pack2(b.x, b.y), pack2(b.z, b.w));
        uint2 pc = make_uint2(pack2(c.x, c.y), pack2(c.z, c.w));
        uint2 pd = make_uint2(pack2(d.x, d.y), pack2(d.z, d.w));
        *(uint2*)swzp(sm.x1, row, 768, 2 * c4)       = pa;
        *(uint2*)swzp(sm.x1, row, 768, 128 + 2 * c4) = pb;
        *(uint2*)swzp(sm.x1, row, 768, 256 + 2 * c4) = pc;
        *(uint2*)swzp(sm.x1, row, 768, 384 + 2 * c4) = pd;
    }
    {   // winding MLP: Linear(2->128)+LN+ReLU, 4 threads/row
        int row = tid >> 2;
        int seg = tid & 3;
        size_t e = e0 + row; if (e >= E_TOTAL) e = E_TOTAL - 1;
        float wi0 = winding[e * 2], wi1 = winding[e * 2 + 1];
        float vals[32]; float s = 0.f, s2 = 0.f;
        #pragma unroll
        for (int j = 0; j < 32; ++j) {
            int jj = seg * 32 + j;
            float v = fmaf(wi0, sm.par[2 * jj], fmaf(wi1, sm.par[2 * jj + 1], sm.par[256 + jj]));
            vals[j] = v; s += v; s2 += v * v;
        }
        s  += __shfl_xor(s, 1);  s  += __shfl_xor(s, 2);
        s2 += __shfl_xor(s2, 1); s2 += __shfl_xor(s2, 2);
        float mean = s * (1.f / 128.f);
        float var  = fmaxf(s2 * (1.f / 128.f) - mean * mean, 0.f);
        float inv  = rsqrtf(var + 1e-5f);
        #pragma unroll
        for (int j4 = 0; j4 < 8; ++j4) {
            float v0, v1, v2, v3;
            {
                int jj = seg * 32 + j4 * 4;
                v0 = fmaxf((vals[j4*4+0] - mean) * inv * sm.par[384 + jj]     + sm.par[512 + jj],     0.f);
                v1 = fmaxf((vals[j4*4+1] - mean) * inv * sm.par[384 + jj + 1] + sm.par[512 + jj + 1], 0.f);
                v2 = fmaxf((vals[j4*4+2] - mean) * inv * sm.par[384 + jj + 2] + sm.par[512 + jj + 2], 0.f);
                v3 = fmaxf((vals[j4*4+3] - mean) * inv * sm.par[384 + jj + 3] + sm.par[512 + jj + 3], 0.f);
            }
            uint2 pk = make_uint2(pack2(v0, v1), pack2(v2, v3));
            *(uint2*)swzp(sm.x1, row, 768, 512 + seg * 64 + j4 * 8) = pk;
        }
    }
    lbar();   // staging complete

    f32x4 acc[2][4];
    #pragma unroll
    for (int nt = 0; nt < 2; ++nt)
        #pragma unroll
        for (int mt = 0; mt < 4; ++mt) acc[nt][mt] = (f32x4){0.f, 0.f, 0.f, 0.f};
    {
        const unsigned short* wp = W1bf + (size_t)(wave * 32 + llo) * 384 + lhi * 8;
        #pragma unroll
        for (int ks = 0; ks < 12; ++ks) {
            bf16x8 wf0 = *(const bf16x8*)(wp + ks * 32);
            bf16x8 wf1 = *(const bf16x8*)(wp + 16 * 384 + ks * 32);
            #pragma unroll
            for (int mt = 0; mt < 4; ++mt) {
                bf16x8 xf = *(const bf16x8*)swzp(sm.x1, mt * 16 + llo, 768, ks * 64 + lhi * 16);
                acc[0][mt] = MFMA(wf0, xf, acc[0][mt]);
                acc[1][mt] = MFMA(wf1, xf, acc[1][mt]);
            }
        }
    }
    {   // bias + per-wave LN partials
        float4 b1q0 = *(const float4*)&b1[wave * 32 + lhi * 4];
        float4 b1q1 = *(const float4*)&b1[wave * 32 + 16 + lhi * 4];
        #pragma unroll
        for (int mt = 0; mt < 4; ++mt) {
            float s = 0.f, s2 = 0.f;
            #pragma unroll
            for (int r = 0; r < 4; ++r) {
                float v0 = acc[0][mt][r] + ((const float*)&b1q0)[r];
                float v1 = acc[1][mt][r] + ((const float*)&b1q1)[r];
                acc[0][mt][r] = v0; acc[1][mt][r] = v1;
                s += v0 + v1; s2 += v0 * v0 + v1 * v1;
            }
            s  += __shfl_xor(s, 16);  s  += __shfl_xor(s, 32);
            s2 += __shfl_xor(s2, 16); s2 += __shfl_xor(s2, 32);
            if (lane < 16) { sm.lns[mt * 16 + llo][wave] = s; sm.ln2[mt * 16 + llo][wave] = s2; }
        }
    }
    lbar();   // partials ready

    {   // LN apply + ReLU + direct global y store (bf16)
        float4 g1q0  = *(const float4*)&g1[wave * 32 + lhi * 4];
        float4 g1q1  = *(const float4*)&g1[wave * 32 + 16 + lhi * 4];
        float4 be1q0 = *(const float4*)&beta1[wave * 32 + lhi * 4];
        float4 be1q1 = *(const float4*)&beta1[wave * 32 + 16 + lhi * 4];
        #pragma unroll
        for (int mt = 0; mt < 4; ++mt) {
            int edge = mt * 16 + llo;
            size_t e = e0 + edge;
            float4 sa = *(const float4*)&sm.lns[edge][0];
            float4 ta = *(const float4*)&sm.ln2[edge][0];
            float s  = sa.x + sa.y + sa.z + sa.w;
            float s2 = ta.x + ta.y + ta.z + ta.w;
            float mean = s * (1.f / 128.f);
            float var  = fmaxf(s2 * (1.f / 128.f) - mean * mean, 0.f);
            float inv  = rsqrtf(var + 1e-5f);
            if (e < E_TOTAL) {
                #pragma unroll
                for (int nt = 0; nt < 2; ++nt) {
                    const float4& gq  = nt ? g1q1 : g1q0;
                    const float4& beq = nt ? be1q1 : be1q0;
                    float v0 = fmaxf((acc[nt][mt][0] - mean) * inv * gq.x + beq.x, 0.f);
                    float v1 = fmaxf((acc[nt][mt][1] - mean) * inv * gq.y + beq.y, 0.f);
                    float v2 = fmaxf((acc[nt][mt][2] - mean) * inv * gq.z + beq.z, 0.f);
                    float v3 = fmaxf((acc[nt][mt][3] - mean) * inv * gq.w + beq.w, 0.f);
                    uint2 pk = make_uint2(pack2(v0, v1), pack2(v2, v3));
                    int f = wave * 32 + nt * 16 + lhi * 4;
                    *(uint2*)(ybf + e * 128 + f) = pk;
                }
            }
        }
    }
}

// ---------------- K3: GRU + blend + GEMM3 (64-edge tile, LDS-staged activations) ----------------
struct SmemG {
    union {
        unsigned short y[64][128];      // staged y; dead after GRU MFMA loop
        unsigned short hnew[64][128];   // aliases y after barrier
    } a;                                // 16384
    unsigned short h[64][128];          // staged h (bf16); 16384
};

__global__ __launch_bounds__(256) void gru_kernel(
    const unsigned short* __restrict__ ybf, const float* __restrict__ hin,
    const float* __restrict__ bih, const float* __restrict__ bhh,
    const float* __restrict__ bx,
    const unsigned short* __restrict__ Wihbf, const unsigned short* __restrict__ Whhbf,
    const unsigned short* __restrict__ Wxbf,
    float* __restrict__ xout, float* __restrict__ hout)
{
    __shared__ SmemG sm;
    const int tid  = threadIdx.x;
    const int wave = tid >> 6;        // 0..3; owns features [32w, 32w+32)
    const int lane = tid & 63;
    const int lhi  = lane >> 4;
    const int llo  = lane & 15;
    const size_t e0 = (size_t)blockIdx.x * 64;

    // ---- batch-stage y (bf16 copy) and h (f32 -> bf16 pack), swizzled ----
    #pragma unroll
    for (int it = 0; it < 4; ++it) {
        int q   = it * 256 + tid;            // 1024 16B-chunks
        int row = q >> 4;
        int c   = (q & 15) * 8;              // element offset
        size_t e = e0 + row; if (e >= E_TOTAL) e = E_TOTAL - 1;
        uint4 v = *(const uint4*)(ybf + e * 128 + c);
        *(uint4*)swzp(sm.a.y, row, 256, 2 * c) = v;
    }
    #pragma unroll
    for (int it = 0; it < 8; ++it) {
        int q   = it * 256 + tid;            // 2048 float4-quads
        int row = q >> 5;
        int c4  = (q & 31) << 2;
        size_t e = e0 + row; if (e >= E_TOTAL) e = E_TOTAL - 1;
        float4 v = *(const float4*)(hin + e * 128 + c4);
        uint2 pk = make_uint2(pack2(v.x, v.y), pack2(v.z, v.w));
        *(uint2*)swzp(sm.h, row, 256, 2 * c4) = pk;
    }
    lbar();   // (1) staging complete

    // ---- GRU gates: acc[mt=4][nt=2] per gate; weights streamed from L2 once ----
    f32x4 gr[4][2], gz[4][2], gn[4][2], gh[4][2];
    #pragma unroll
    for (int mt = 0; mt < 4; ++mt)
        #pragma unroll
        for (int nt = 0; nt < 2; ++nt) {
            gr[mt][nt] = (f32x4){0.f,0.f,0.f,0.f}; gz[mt][nt] = (f32x4){0.f,0.f,0.f,0.f};
            gn[mt][nt] = (f32x4){0.f,0.f,0.f,0.f}; gh[mt][nt] = (f32x4){0.f,0.f,0.f,0.f};
        }
    {
        const unsigned short* pi = Wihbf + (size_t)(wave * 32 + llo) * 128 + lhi * 8;
        const unsigned short* pw = Whhbf + (size_t)(wave * 32 + llo) * 128 + lhi * 8;
        #pragma unroll
        for (int ks = 0; ks < 4; ++ks) {
            bf16x8 wr[2], wz[2], wn[2], vr[2], vz[2], vn[2];
            #pragma unroll
            for (int nt = 0; nt < 2; ++nt) {
                const size_t ro = (size_t)nt * 16 * 128 + ks * 32;
                wr[nt] = *(const bf16x8*)(pi + ro);
                wz[nt] = *(const bf16x8*)(pi + 128 * 128 + ro);
                wn[nt] = *(const bf16x8*)(pi + 256 * 128 + ro);
                vr[nt] = *(const bf16x8*)(pw + ro);
                vz[nt] = *(const bf16x8*)(pw + 128 * 128 + ro);
                vn[nt] = *(const bf16x8*)(pw + 256 * 128 + ro);
            }
            #pragma unroll
            for (int mt = 0; mt < 4; ++mt) {
                bf16x8 ay = *(const bf16x8*)swzp(sm.a.y, mt * 16 + llo, 256, ks * 64 + lhi * 16);
                bf16x8 ah = *(const bf16x8*)swzp(sm.h,   mt * 16 + llo, 256, ks * 64 + lhi * 16);
                #pragma unroll
                for (int nt = 0; nt < 2; ++nt) {
                    gr[mt][nt] = MFMA(wr[nt], ay, gr[mt][nt]);
                    gr[mt][nt] = MFMA(vr[nt], ah, gr[mt][nt]);
                    gz[mt][nt] = MFMA(wz[nt], ay, gz[mt][nt]);
                    gz[mt][nt] = MFMA(vz[nt], ah, gz[mt][nt]);
                    gn[mt][nt] = MFMA(wn[nt], ay, gn[mt][nt]);
                    gh[mt][nt] = MFMA(vn[nt], ah, gh[mt][nt]);
                }
            }
        }
    }
    lbar();   // (2) y reads done -> hnew may alias y

    // ---- epilogue: gates + blend (exact f32 h from L2-hot global) + hout + hnew->LDS ----
    #pragma unroll
    for (int nt = 0; nt < 2; ++nt) {
        int f = wave * 32 + nt * 16 + lhi * 4;
        float4 bi0 = *(const float4*)&bih[f];
        float4 bi1 = *(const float4*)&bih[128 + f];
        float4 bi2 = *(const float4*)&bih[256 + f];
        float4 bh0 = *(const float4*)&bhh[f];
        float4 bh1 = *(const float4*)&bhh[128 + f];
        float4 bh2 = *(const float4*)&bhh[256 + f];
        #pragma unroll
        for (int mt = 0; mt < 4; ++mt) {
            size_t e = e0 + mt * 16 + llo;
            size_t ec = e < E_TOTAL ? e : E_TOTAL - 1;
            float4 hv = *(const float4*)(hin + ec * 128 + f);
            float4 ho;
            #pragma unroll
            for (int r = 0; r < 4; ++r) {
                float rr = sigm(gr[mt][nt][r] + ((const float*)&bi0)[r] + ((const float*)&bh0)[r]);
                float zz = sigm(gz[mt][nt][r] + ((const float*)&bi1)[r] + ((const float*)&bh1)[r]);
                float nn = tanh_fast(gn[mt][nt][r] + ((const float*)&bi2)[r]
                                     + rr * (gh[mt][nt][r] + ((const float*)&bh2)[r]));
                ((float*)&ho)[r] = (1.f - zz) * nn + zz * ((const float*)&hv)[r];
            }
            if (e < E_TOTAL) *(float4*)(hout + e * 128 + f) = ho;
            uint2 pk = make_uint2(pack2(ho.x, ho.y), pack2(ho.z, ho.w));
            *(uint2*)swzp(sm.a.hnew, mt * 16 + llo, 256, 2 * f) = pk;
        }
    }
    lbar();   // (3) hnew complete

    // ---- GEMM3: Wx rows [16w,16w+16) x 64 edges; direct xout stores ----
    {
        f32x4 a3[4];
        #pragma unroll
        for (int mt = 0; mt < 4; ++mt) a3[mt] = (f32x4){0.f,0.f,0.f,0.f};
        const unsigned short* px = Wxbf + (size_t)(wave * 16 + llo) * 128 + lhi * 8;
        #pragma unroll
        for (int ks = 0; ks < 4; ++ks) {
            bf16x8 wf = *(const bf16x8*)(px + ks * 32);
            #pragma unroll
            for (int mt = 0; mt < 4; ++mt) {
                bf16x8 bh = *(const bf16x8*)swzp(sm.a.hnew, mt * 16 + llo, 256, ks * 64 + lhi * 16);
                a3[mt] = MFMA(wf, bh, a3[mt]);
            }
        }
        int fx = wave * 16 + lhi * 4;
        float4 bq = *(const float4*)&bx[fx];
        #pragma unroll
        for (int mt = 0; mt < 4; ++mt) {
            size_t e = e0 + mt * 16 + llo;
            float4 o;
            o.x = a3[mt][0] + bq.x; o.y = a3[mt][1] + bq.y;
            o.z = a3[mt][2] + bq.z; o.w = a3[mt][3] + bq.w;
            if (e < E_TOTAL) *(float4*)(xout + e * 64 + fx) = o;
        }
    }
}

extern "C" void kernel_launch(void* const* d_in, const int* in_sizes, int n_in,
                              void* d_out, int out_size, void* d_ws, size_t ws_size,
                              hipStream_t stream)
{
    const float* src   = (const float*)d_in[0];
    const float* dst   = (const float*)d_in[1];
    const float* eat   = (const float*)d_in[2];
    const float* hin   = (const float*)d_in[3];
    const float* u     = (const float*)d_in[4];
    const int*   bat   = (const int*)d_in[5];
    const float* wind  = (const float*)d_in[6];
    const float* Ww    = (const float*)d_in[7];
    const float* bw    = (const float*)d_in[8];
    const float* gw    = (const float*)d_in[9];
    const float* betaw = (const float*)d_in[10];
    const float* W1    = (const float*)d_in[11];
    const float* b1    = (const float*)d_in[12];
    const float* g1    = (const float*)d_in[13];
    const float* beta1 = (const float*)d_in[14];
    const float* Wih   = (const float*)d_in[15];
    const float* Whh   = (const float*)d_in[16];
    const float* bih   = (const float*)d_in[17];
    const float* bhh   = (const float*)d_in[18];
    const float* Wx    = (const float*)d_in[19];
    const float* bx    = (const float*)d_in[20];

    // workspace layout: y (E*128 bf16 = 128 MB) | weights bf16 (304 KB)
    unsigned short* ybf  = (unsigned short*)d_ws;
    unsigned short* wbuf = ybf + 64000000ull;

    wconv_kernel<<<608, 256, 0, stream>>>(W1, Wih, Whh, Wx, wbuf);

    float* xout = (float*)d_out;
    float* hout = xout + (size_t)E_TOTAL * 64;

    mlp1_kernel<<<NB2, 256, 0, stream>>>(
        src, dst, eat, u, bat, wind, Ww, bw, gw, betaw,
        b1, g1, beta1, wbuf, ybf);

    gru_kernel<<<NB3, 256, 0, stream>>>(
        ybf, hin, bih, bhh, bx,
        wbuf + 49152, wbuf + 98304, wbuf + 147456,
        xout, hout);
}

// Round 14
// 582.517 us; speedup vs baseline: 6.1695x; 1.3053x over previous
//
#include <hip/hip_runtime.h>
#include <hip/hip_bf16.h>

#define E_TOTAL 500000
#define NB2 7813     // mlp1 blocks (64-edge tiles)
#define NTIL 7813    // gru tiles (64 edges)
#define GBLK 256     // persistent gru blocks

typedef __attribute__((ext_vector_type(8))) short bf16x8;
typedef __attribute__((ext_vector_type(4))) float f32x4;

#define MFMA(a, b, c) __builtin_amdgcn_mfma_f32_16x16x32_bf16((a), (b), (c), 0, 0, 0)

typedef __attribute__((address_space(1))) const void GV;
typedef __attribute__((address_space(3))) void LV;

// Barrier with LDS-only drain: global loads/stores stay in flight.
__device__ __forceinline__ void lbar() {
    asm volatile("s_waitcnt lgkmcnt(0)" ::: "memory");
    __builtin_amdgcn_s_barrier();
}
// pack two f32 -> two bf16 (round-half-up) via v_perm
__device__ __forceinline__ unsigned int pack2(float x, float y) {
    unsigned int xb = __builtin_bit_cast(unsigned int, x) + 0x8000u;
    unsigned int yb = __builtin_bit_cast(unsigned int, y) + 0x8000u;
    return __builtin_amdgcn_perm(yb, xb, 0x07060302u);
}
__device__ __forceinline__ float sigm(float x) { return 1.f / (1.f + __expf(-x)); }
__device__ __forceinline__ float tanh_fast(float x) {
    float t = __expf(-2.f * x);
    return (1.f - t) / (1.f + t);
}
// XOR-swizzled LDS address (T2)
__device__ __forceinline__ char* swzp(void* base, int row, int rowBytes, int colByte) {
    return (char*)base + row * rowBytes + (colByte ^ ((row & 7) << 4));
}

// ---------------- K1: weights f32 -> bf16 ----------------
__global__ void wconv_kernel(const float* __restrict__ W1, const float* __restrict__ Wih,
                             const float* __restrict__ Whh, const float* __restrict__ Wx,
                             unsigned short* __restrict__ out) {
    int i = blockIdx.x * 256 + threadIdx.x;
    if (i >= 155648) return;
    float v;
    if      (i < 49152)  v = W1[i];
    else if (i < 98304)  v = Wih[i - 49152];
    else if (i < 147456) v = Whh[i - 98304];
    else                 v = Wx[i - 147456];
    unsigned int b = __builtin_bit_cast(unsigned int, v) + 0x8000u;
    out[i] = (unsigned short)(b >> 16);
}

// ---------------- K2: concat + winding MLP + GEMM1 + LN + ReLU -> y (bf16) ----------------
struct SmemM {
    unsigned short x1[64][384];
    float lns[64][4];
    float ln2[64][4];
    float par[640];
};

__global__ __launch_bounds__(256) void mlp1_kernel(
    const float* __restrict__ src, const float* __restrict__ dst,
    const float* __restrict__ eat, const float* __restrict__ u,
    const int* __restrict__ batch, const float* __restrict__ winding,
    const float* __restrict__ Ww, const float* __restrict__ bw,
    const float* __restrict__ gw, const float* __restrict__ betaw,
    const float* __restrict__ b1, const float* __restrict__ g1,
    const float* __restrict__ beta1,
    const unsigned short* __restrict__ W1bf,
    unsigned short* __restrict__ ybf)
{
    __shared__ SmemM sm;
    const int tid  = threadIdx.x;
    const int wave = tid >> 6;
    const int lane = tid & 63;
    const int lhi  = lane >> 4;
    const int llo  = lane & 15;
    const size_t e0 = (size_t)blockIdx.x * 64;

    for (int i = tid; i < 640; i += 256) {
        float v;
        if      (i < 256) v = Ww[i];
        else if (i < 384) v = bw[i - 256];
        else if (i < 512) v = gw[i - 384];
        else              v = betaw[i - 512];
        sm.par[i] = v;
    }
    lbar();

    #pragma unroll
    for (int it = 0; it < 4; ++it) {
        int q   = it * 256 + tid;
        int row = q >> 4;
        int c4  = (q & 15) << 2;
        size_t e = e0 + row; if (e >= E_TOTAL) e = E_TOTAL - 1;
        float4 a = *(const float4*)(src + e * 64 + c4);
        float4 b = *(const float4*)(dst + e * 64 + c4);
        float4 c = *(const float4*)(eat + e * 64 + c4);
        int bi   = batch[e];
        float4 d = *(const float4*)(u + (size_t)bi * 64 + c4);
        uint2 pa = make_uint2(pack2(a.x, a.y), pack2(a.z, a.w));
        uint2 pb = make_uint2(pack2(b.x, b.y), pack2(b.z, b.w));
        uint2 pc = make_uint2(pack2(c.x, c.y), pack2(c.z, c.w));
        uint2 pd = make_uint2(pack2(d.x, d.y), pack2(d.z, d.w));
        *(uint2*)swzp(sm.x1, row, 768, 2 * c4)       = pa;
        *(uint2*)swzp(sm.x1, row, 768, 128 + 2 * c4) = pb;
        *(uint2*)swzp(sm.x1, row, 768, 256 + 2 * c4) = pc;
        *(uint2*)swzp(sm.x1, row, 768, 384 + 2 * c4) = pd;
    }
    {   // winding MLP
        int row = tid >> 2;
        int seg = tid & 3;
        size_t e = e0 + row; if (e >= E_TOTAL) e = E_TOTAL - 1;
        float wi0 = winding[e * 2], wi1 = winding[e * 2 + 1];
        float vals[32]; float s = 0.f, s2 = 0.f;
        #pragma unroll
        for (int j = 0; j < 32; ++j) {
            int jj = seg * 32 + j;
            float v = fmaf(wi0, sm.par[2 * jj], fmaf(wi1, sm.par[2 * jj + 1], sm.par[256 + jj]));
            vals[j] = v; s += v; s2 += v * v;
        }
        s  += __shfl_xor(s, 1);  s  += __shfl_xor(s, 2);
        s2 += __shfl_xor(s2, 1); s2 += __shfl_xor(s2, 2);
        float mean = s * (1.f / 128.f);
        float var  = fmaxf(s2 * (1.f / 128.f) - mean * mean, 0.f);
        float inv  = rsqrtf(var + 1e-5f);
        #pragma unroll
        for (int j4 = 0; j4 < 8; ++j4) {
            int jj = seg * 32 + j4 * 4;
            float v0 = fmaxf((vals[j4*4+0] - mean) * inv * sm.par[384 + jj]     + sm.par[512 + jj],     0.f);
            float v1 = fmaxf((vals[j4*4+1] - mean) * inv * sm.par[384 + jj + 1] + sm.par[512 + jj + 1], 0.f);
            float v2 = fmaxf((vals[j4*4+2] - mean) * inv * sm.par[384 + jj + 2] + sm.par[512 + jj + 2], 0.f);
            float v3 = fmaxf((vals[j4*4+3] - mean) * inv * sm.par[384 + jj + 3] + sm.par[512 + jj + 3], 0.f);
            uint2 pk = make_uint2(pack2(v0, v1), pack2(v2, v3));
            *(uint2*)swzp(sm.x1, row, 768, 512 + seg * 64 + j4 * 8) = pk;
        }
    }
    lbar();

    f32x4 acc[2][4];
    #pragma unroll
    for (int nt = 0; nt < 2; ++nt)
        #pragma unroll
        for (int mt = 0; mt < 4; ++mt) acc[nt][mt] = (f32x4){0.f, 0.f, 0.f, 0.f};
    {
        const unsigned short* wp = W1bf + (size_t)(wave * 32 + llo) * 384 + lhi * 8;
        #pragma unroll
        for (int ks = 0; ks < 12; ++ks) {
            bf16x8 wf0 = *(const bf16x8*)(wp + ks * 32);
            bf16x8 wf1 = *(const bf16x8*)(wp + 16 * 384 + ks * 32);
            #pragma unroll
            for (int mt = 0; mt < 4; ++mt) {
                bf16x8 xf = *(const bf16x8*)swzp(sm.x1, mt * 16 + llo, 768, ks * 64 + lhi * 16);
                acc[0][mt] = MFMA(wf0, xf, acc[0][mt]);
                acc[1][mt] = MFMA(wf1, xf, acc[1][mt]);
            }
        }
    }
    {
        float4 b1q0 = *(const float4*)&b1[wave * 32 + lhi * 4];
        float4 b1q1 = *(const float4*)&b1[wave * 32 + 16 + lhi * 4];
        #pragma unroll
        for (int mt = 0; mt < 4; ++mt) {
            float s = 0.f, s2 = 0.f;
            #pragma unroll
            for (int r = 0; r < 4; ++r) {
                float v0 = acc[0][mt][r] + ((const float*)&b1q0)[r];
                float v1 = acc[1][mt][r] + ((const float*)&b1q1)[r];
                acc[0][mt][r] = v0; acc[1][mt][r] = v1;
                s += v0 + v1; s2 += v0 * v0 + v1 * v1;
            }
            s  += __shfl_xor(s, 16);  s  += __shfl_xor(s, 32);
            s2 += __shfl_xor(s2, 16); s2 += __shfl_xor(s2, 32);
            if (lane < 16) { sm.lns[mt * 16 + llo][wave] = s; sm.ln2[mt * 16 + llo][wave] = s2; }
        }
    }
    lbar();

    {
        float4 g1q0  = *(const float4*)&g1[wave * 32 + lhi * 4];
        float4 g1q1  = *(const float4*)&g1[wave * 32 + 16 + lhi * 4];
        float4 be1q0 = *(const float4*)&beta1[wave * 32 + lhi * 4];
        float4 be1q1 = *(const float4*)&beta1[wave * 32 + 16 + lhi * 4];
        #pragma unroll
        for (int mt = 0; mt < 4; ++mt) {
            int edge = mt * 16 + llo;
            size_t e = e0 + edge;
            float4 sa = *(const float4*)&sm.lns[edge][0];
            float4 ta = *(const float4*)&sm.ln2[edge][0];
            float s  = sa.x + sa.y + sa.z + sa.w;
            float s2 = ta.x + ta.y + ta.z + ta.w;
            float mean = s * (1.f / 128.f);
            float var  = fmaxf(s2 * (1.f / 128.f) - mean * mean, 0.f);
            float inv  = rsqrtf(var + 1e-5f);
            if (e < E_TOTAL) {
                #pragma unroll
                for (int nt = 0; nt < 2; ++nt) {
                    const float4& gq  = nt ? g1q1 : g1q0;
                    const float4& beq = nt ? be1q1 : be1q0;
                    float v0 = fmaxf((acc[nt][mt][0] - mean) * inv * gq.x + beq.x, 0.f);
                    float v1 = fmaxf((acc[nt][mt][1] - mean) * inv * gq.y + beq.y, 0.f);
                    float v2 = fmaxf((acc[nt][mt][2] - mean) * inv * gq.z + beq.z, 0.f);
                    float v3 = fmaxf((acc[nt][mt][3] - mean) * inv * gq.w + beq.w, 0.f);
                    uint2 pk = make_uint2(pack2(v0, v1), pack2(v2, v3));
                    int f = wave * 32 + nt * 16 + lhi * 4;
                    *(uint2*)(ybf + e * 128 + f) = pk;
                }
            }
        }
    }
}

// ---------------- K3: persistent GRU + blend + GEMM3, DMA double-buffered ----------------
// 512 threads (8 waves, each owns 16 features), 64-edge tiles, 96 KB LDS.
__global__ __launch_bounds__(512, 1) void gru_kernel(
    const unsigned short* __restrict__ ybf, const float* __restrict__ hin,
    const float* __restrict__ bih, const float* __restrict__ bhh,
    const float* __restrict__ bx,
    const unsigned short* __restrict__ Wihbf, const unsigned short* __restrict__ Whhbf,
    const unsigned short* __restrict__ Wxbf,
    float* __restrict__ xout, float* __restrict__ hout)
{
    __shared__ unsigned short smy[2][64][128];   // y buffers (hnew aliases smy[cur] late)
    __shared__ float          smh[2][64][128];   // h buffers (f32)
    const int tid  = threadIdx.x;
    const int wave = tid >> 6;        // 0..7; owns features [16w, 16w+16)
    const int lane = tid & 63;
    const int lhi  = lane >> 4;
    const int llo  = lane & 15;
    const int f    = wave * 16 + lhi * 4;      // GRU feature base
    const int fx   = (wave & 3) * 16 + lhi * 4; // GEMM3 feature base
    const int eh   = (wave >> 2) * 32;          // GEMM3 edge half

    // loop-invariant params
    const float4 bi0 = *(const float4*)&bih[f];
    const float4 bi1 = *(const float4*)&bih[128 + f];
    const float4 bi2 = *(const float4*)&bih[256 + f];
    const float4 bh0 = *(const float4*)&bhh[f];
    const float4 bh1 = *(const float4*)&bhh[128 + f];
    const float4 bh2 = *(const float4*)&bhh[256 + f];
    const float4 bxq = *(const float4*)&bx[fx];
    const unsigned short* pi = Wihbf + (size_t)(wave * 16 + llo) * 128 + lhi * 8;
    const unsigned short* pw = Whhbf + (size_t)(wave * 16 + llo) * 128 + lhi * 8;
    const unsigned short* px = Wxbf + (size_t)((wave & 3) * 16 + llo) * 128 + lhi * 8;

    // DMA stage: inverse-swizzled global source -> linear LDS dest (rule #21)
    auto stage = [&](int t, int buf) {
        const size_t eb = (size_t)t * 64;
        #pragma unroll
        for (int j = 0; j < 2; ++j) {          // y: 16 KB, 2 rounds of 8 KB
            int O = j * 8192 + tid * 16;
            int row = O >> 8, colB = O & 255;
            size_t e = eb + row; if (e >= E_TOTAL) e = E_TOTAL - 1;
            unsigned lc = (unsigned)colB ^ (((unsigned)row & 7u) << 4);
            const char* gp = (const char*)ybf + e * 256 + lc;
            char* lp = (char*)&smy[buf][0][0] + O;
            __builtin_amdgcn_global_load_lds((GV*)gp, (LV*)lp, 16, 0, 0);
        }
        #pragma unroll
        for (int j = 0; j < 4; ++j) {          // h: 32 KB, 4 rounds of 8 KB
            int O = j * 8192 + tid * 16;
            int row = O >> 9, colB = O & 511;
            size_t e = eb + row; if (e >= E_TOTAL) e = E_TOTAL - 1;
            unsigned lc = (unsigned)colB ^ (((unsigned)row & 7u) << 4);
            const char* gp = (const char*)hin + e * 512 + lc;
            char* lp = (char*)&smh[buf][0][0] + O;
            __builtin_amdgcn_global_load_lds((GV*)gp, (LV*)lp, 16, 0, 0);
        }
    };

    int cur = 0;
    stage(blockIdx.x, 0);
    asm volatile("s_waitcnt vmcnt(0)" ::: "memory");
    lbar();

    for (int t = blockIdx.x; t < NTIL; t += GBLK) {
        const size_t e0 = (size_t)t * 64;
        {   // prefetch next tile into the other buffer (its readers finished at bottom lbar)
            int tn = t + GBLK; if (tn >= NTIL) tn = t;
            stage(tn, cur ^ 1);
        }

        // ---- GRU gates: acc[mt=4] per gate (nt=1), weights from L2 ----
        f32x4 gr[4], gz[4], gn[4], gh[4];
        #pragma unroll
        for (int mt = 0; mt < 4; ++mt) {
            gr[mt] = (f32x4){0.f,0.f,0.f,0.f}; gz[mt] = (f32x4){0.f,0.f,0.f,0.f};
            gn[mt] = (f32x4){0.f,0.f,0.f,0.f}; gh[mt] = (f32x4){0.f,0.f,0.f,0.f};
        }
        #pragma unroll
        for (int ks = 0; ks < 4; ++ks) {
            bf16x8 wr = *(const bf16x8*)(pi + ks * 32);
            bf16x8 wz = *(const bf16x8*)(pi + 128 * 128 + ks * 32);
            bf16x8 wn = *(const bf16x8*)(pi + 256 * 128 + ks * 32);
            bf16x8 vr = *(const bf16x8*)(pw + ks * 32);
            bf16x8 vz = *(const bf16x8*)(pw + 128 * 128 + ks * 32);
            bf16x8 vn = *(const bf16x8*)(pw + 256 * 128 + ks * 32);
            #pragma unroll
            for (int mt = 0; mt < 4; ++mt) {
                int row = mt * 16 + llo;
                bf16x8 ay = *(const bf16x8*)swzp(smy[cur], row, 256, ks * 64 + lhi * 16);
                float4 q0 = *(const float4*)swzp(smh[cur], row, 512, ks * 128 + lhi * 32);
                float4 q1 = *(const float4*)swzp(smh[cur], row, 512, ks * 128 + lhi * 32 + 16);
                uint4 up;
                up.x = pack2(q0.x, q0.y); up.y = pack2(q0.z, q0.w);
                up.z = pack2(q1.x, q1.y); up.w = pack2(q1.z, q1.w);
                bf16x8 ah = __builtin_bit_cast(bf16x8, up);
                gr[mt] = MFMA(wr, ay, gr[mt]);  gr[mt] = MFMA(vr, ah, gr[mt]);
                gz[mt] = MFMA(wz, ay, gz[mt]);  gz[mt] = MFMA(vz, ah, gz[mt]);
                gn[mt] = MFMA(wn, ay, gn[mt]);  gh[mt] = MFMA(vn, ah, gh[mt]);
            }
        }
        lbar();   // (B) all y reads done -> hnew may alias smy[cur]

        // ---- epilogue: gates + blend (f32 h from LDS) + hout store + hnew -> LDS ----
        #pragma unroll
        for (int mt = 0; mt < 4; ++mt) {
            int row = mt * 16 + llo;
            float4 hv = *(const float4*)swzp(smh[cur], row, 512, 4 * f);
            float4 ho;
            #pragma unroll
            for (int r = 0; r < 4; ++r) {
                float rr = sigm(gr[mt][r] + ((const float*)&bi0)[r] + ((const float*)&bh0)[r]);
                float zz = sigm(gz[mt][r] + ((const float*)&bi1)[r] + ((const float*)&bh1)[r]);
                float nn = tanh_fast(gn[mt][r] + ((const float*)&bi2)[r]
                                     + rr * (gh[mt][r] + ((const float*)&bh2)[r]));
                ((float*)&ho)[r] = (1.f - zz) * nn + zz * ((const float*)&hv)[r];
            }
            ushort4 pk;
            pk.x = (unsigned short)(pack2(ho.x, ho.y) & 0xffffu);
            pk.y = (unsigned short)(pack2(ho.x, ho.y) >> 16);
            pk.z = (unsigned short)(pack2(ho.z, ho.w) & 0xffffu);
            pk.w = (unsigned short)(pack2(ho.z, ho.w) >> 16);
            *(ushort4*)swzp(smy[cur], row, 256, 2 * f) = pk;
            size_t e = e0 + row;
            if (e < E_TOTAL) *(float4*)(hout + e * 128 + f) = ho;
        }
        lbar();   // (C) hnew complete

        // ---- GEMM3: Wx rows [16(w&3),+16) x 32 edges of this wave's half ----
        {
            f32x4 a3[2];
            a3[0] = (f32x4){0.f,0.f,0.f,0.f}; a3[1] = (f32x4){0.f,0.f,0.f,0.f};
            #pragma unroll
            for (int ks = 0; ks < 4; ++ks) {
                bf16x8 wf = *(const bf16x8*)(px + ks * 32);
                #pragma unroll
                for (int mt = 0; mt < 2; ++mt) {
                    bf16x8 bh = *(const bf16x8*)swzp(smy[cur], eh + mt * 16 + llo, 256, ks * 64 + lhi * 16);
                    a3[mt] = MFMA(wf, bh, a3[mt]);
                }
            }
            #pragma unroll
            for (int mt = 0; mt < 2; ++mt) {
                size_t e = e0 + eh + mt * 16 + llo;
                float4 o;
                o.x = a3[mt][0] + bxq.x; o.y = a3[mt][1] + bxq.y;
                o.z = a3[mt][2] + bxq.z; o.w = a3[mt][3] + bxq.w;
                if (e < E_TOTAL) *(float4*)(xout + e * 64 + fx) = o;
            }
        }

        // bottom: wait prefetch DMA retired (counted — never drain in-flight stores fully)
        asm volatile("s_waitcnt vmcnt(6)" ::: "memory");
        lbar();
        cur ^= 1;
    }
}

extern "C" void kernel_launch(void* const* d_in, const int* in_sizes, int n_in,
                              void* d_out, int out_size, void* d_ws, size_t ws_size,
                              hipStream_t stream)
{
    const float* src   = (const float*)d_in[0];
    const float* dst   = (const float*)d_in[1];
    const float* eat   = (const float*)d_in[2];
    const float* hin   = (const float*)d_in[3];
    const float* u     = (const float*)d_in[4];
    const int*   bat   = (const int*)d_in[5];
    const float* wind  = (const float*)d_in[6];
    const float* Ww    = (const float*)d_in[7];
    const float* bw    = (const float*)d_in[8];
    const float* gw    = (const float*)d_in[9];
    const float* betaw = (const float*)d_in[10];
    const float* W1    = (const float*)d_in[11];
    const float* b1    = (const float*)d_in[12];
    const float* g1    = (const float*)d_in[13];
    const float* beta1 = (const float*)d_in[14];
    const float* Wih   = (const float*)d_in[15];
    const float* Whh   = (const float*)d_in[16];
    const float* bih   = (const float*)d_in[17];
    const float* bhh   = (const float*)d_in[18];
    const float* Wx    = (const float*)d_in[19];
    const float* bx    = (const float*)d_in[20];

    // workspace layout: y (E*128 bf16 = 128 MB) | weights bf16 (304 KB)
    unsigned short* ybf  = (unsigned short*)d_ws;
    unsigned short* wbuf = ybf + 64000000ull;

    wconv_kernel<<<608, 256, 0, stream>>>(W1, Wih, Whh, Wx, wbuf);

    float* xout = (float*)d_out;
    float* hout = xout + (size_t)E_TOTAL * 64;

    mlp1_kernel<<<NB2, 256, 0, stream>>>(
        src, dst, eat, u, bat, wind, Ww, bw, gw, betaw,
        b1, g1, beta1, wbuf, ybf);

    gru_kernel<<<GBLK, 512, 0, stream>>>(
        ybf, hin, bih, bhh, bx,
        wbuf + 49152, wbuf + 98304, wbuf + 147456,
        xout, hout);
}

// Round 15
// 503.700 us; speedup vs baseline: 7.1349x; 1.1565x over previous
//
#include <hip/hip_runtime.h>
#include <hip/hip_bf16.h>

#define E_TOTAL 500000
#define NB2 7813     // mlp1 blocks (64-edge tiles)
#define NTIL 7813    // gru tiles (64 edges)
#define GBLK 512     // persistent gru blocks (2 blocks/CU)

typedef __attribute__((ext_vector_type(8))) short bf16x8;
typedef __attribute__((ext_vector_type(4))) float f32x4;

#define MFMA(a, b, c) __builtin_amdgcn_mfma_f32_16x16x32_bf16((a), (b), (c), 0, 0, 0)

typedef __attribute__((address_space(1))) const void GV;
typedef __attribute__((address_space(3))) void LV;

// Barrier with LDS-only drain: global loads/stores stay in flight.
__device__ __forceinline__ void lbar() {
    asm volatile("s_waitcnt lgkmcnt(0)" ::: "memory");
    __builtin_amdgcn_s_barrier();
}
// pack two f32 -> two bf16 (round-half-up) via v_perm
__device__ __forceinline__ unsigned int pack2(float x, float y) {
    unsigned int xb = __builtin_bit_cast(unsigned int, x) + 0x8000u;
    unsigned int yb = __builtin_bit_cast(unsigned int, y) + 0x8000u;
    return __builtin_amdgcn_perm(yb, xb, 0x07060302u);
}
__device__ __forceinline__ float b2f(unsigned short s) {
    return __bfloat162float(__builtin_bit_cast(__hip_bfloat16, s));
}
__device__ __forceinline__ float sigm(float x) { return 1.f / (1.f + __expf(-x)); }
__device__ __forceinline__ float tanh_fast(float x) {
    float t = __expf(-2.f * x);
    return (1.f - t) / (1.f + t);
}
// XOR-swizzled LDS address (T2)
__device__ __forceinline__ char* swzp(void* base, int row, int rowBytes, int colByte) {
    return (char*)base + row * rowBytes + (colByte ^ ((row & 7) << 4));
}

// ---------------- K1: weights f32 -> bf16 ----------------
__global__ void wconv_kernel(const float* __restrict__ W1, const float* __restrict__ Wih,
                             const float* __restrict__ Whh, const float* __restrict__ Wx,
                             unsigned short* __restrict__ out) {
    int i = blockIdx.x * 256 + threadIdx.x;
    if (i >= 155648) return;
    float v;
    if      (i < 49152)  v = W1[i];
    else if (i < 98304)  v = Wih[i - 49152];
    else if (i < 147456) v = Whh[i - 98304];
    else                 v = Wx[i - 147456];
    unsigned int b = __builtin_bit_cast(unsigned int, v) + 0x8000u;
    out[i] = (unsigned short)(b >> 16);
}

// ---------------- K2: concat + winding MLP + GEMM1 + LN + ReLU -> y ; h -> hbf ----------------
struct SmemM {
    unsigned short x1[64][384];
    float lns[64][4];
    float ln2[64][4];
    float par[640];
};

__global__ __launch_bounds__(256) void mlp1_kernel(
    const float* __restrict__ src, const float* __restrict__ dst,
    const float* __restrict__ eat, const float* __restrict__ u,
    const int* __restrict__ batch, const float* __restrict__ winding,
    const float* __restrict__ hin,
    const float* __restrict__ Ww, const float* __restrict__ bw,
    const float* __restrict__ gw, const float* __restrict__ betaw,
    const float* __restrict__ b1, const float* __restrict__ g1,
    const float* __restrict__ beta1,
    const unsigned short* __restrict__ W1bf,
    unsigned short* __restrict__ ybf, unsigned short* __restrict__ hbf)
{
    __shared__ SmemM sm;
    const int tid  = threadIdx.x;
    const int wave = tid >> 6;
    const int lane = tid & 63;
    const int lhi  = lane >> 4;
    const int llo  = lane & 15;
    const size_t e0 = (size_t)blockIdx.x * 64;

    for (int i = tid; i < 640; i += 256) {
        float v;
        if      (i < 256) v = Ww[i];
        else if (i < 384) v = bw[i - 256];
        else if (i < 512) v = gw[i - 384];
        else              v = betaw[i - 512];
        sm.par[i] = v;
    }
    lbar();

    #pragma unroll
    for (int it = 0; it < 4; ++it) {
        int q   = it * 256 + tid;
        int row = q >> 4;
        int c4  = (q & 15) << 2;
        size_t e = e0 + row; if (e >= E_TOTAL) e = E_TOTAL - 1;
        float4 a = *(const float4*)(src + e * 64 + c4);
        float4 b = *(const float4*)(dst + e * 64 + c4);
        float4 c = *(const float4*)(eat + e * 64 + c4);
        int bi   = batch[e];
        float4 d = *(const float4*)(u + (size_t)bi * 64 + c4);
        uint2 pa = make_uint2(pack2(a.x, a.y), pack2(a.z, a.w));
        uint2 pb = make_uint2(pack2(b.x, b.y), pack2(b.z, b.w));
        uint2 pc = make_uint2(pack2(c.x, c.y), pack2(c.z, c.w));
        uint2 pd = make_uint2(pack2(d.x, d.y), pack2(d.z, d.w));
        *(uint2*)swzp(sm.x1, row, 768, 2 * c4)       = pa;
        *(uint2*)swzp(sm.x1, row, 768, 128 + 2 * c4) = pb;
        *(uint2*)swzp(sm.x1, row, 768, 256 + 2 * c4) = pc;
        *(uint2*)swzp(sm.x1, row, 768, 384 + 2 * c4) = pd;
    }
    // ---- h f32 -> bf16 conversion for this tile (independent; overlaps GEMM1 latency) ----
    #pragma unroll
    for (int it = 0; it < 4; ++it) {
        int q   = it * 256 + tid;          // 1024 chunks of 8 floats
        int row = q >> 4;
        int c8  = (q & 15) << 3;
        size_t e = e0 + row;
        size_t ec = e < E_TOTAL ? e : E_TOTAL - 1;
        float4 a = *(const float4*)(hin + ec * 128 + c8);
        float4 b = *(const float4*)(hin + ec * 128 + c8 + 4);
        uint4 pk;
        pk.x = pack2(a.x, a.y); pk.y = pack2(a.z, a.w);
        pk.z = pack2(b.x, b.y); pk.w = pack2(b.z, b.w);
        if (e < E_TOTAL) *(uint4*)(hbf + e * 128 + c8) = pk;
    }
    {   // winding MLP
        int row = tid >> 2;
        int seg = tid & 3;
        size_t e = e0 + row; if (e >= E_TOTAL) e = E_TOTAL - 1;
        float wi0 = winding[e * 2], wi1 = winding[e * 2 + 1];
        float vals[32]; float s = 0.f, s2 = 0.f;
        #pragma unroll
        for (int j = 0; j < 32; ++j) {
            int jj = seg * 32 + j;
            float v = fmaf(wi0, sm.par[2 * jj], fmaf(wi1, sm.par[2 * jj + 1], sm.par[256 + jj]));
            vals[j] = v; s += v; s2 += v * v;
        }
        s  += __shfl_xor(s, 1);  s  += __shfl_xor(s, 2);
        s2 += __shfl_xor(s2, 1); s2 += __shfl_xor(s2, 2);
        float mean = s * (1.f / 128.f);
        float var  = fmaxf(s2 * (1.f / 128.f) - mean * mean, 0.f);
        float inv  = rsqrtf(var + 1e-5f);
        #pragma unroll
        for (int j4 = 0; j4 < 8; ++j4) {
            int jj = seg * 32 + j4 * 4;
            float v0 = fmaxf((vals[j4*4+0] - mean) * inv * sm.par[384 + jj]     + sm.par[512 + jj],     0.f);
            float v1 = fmaxf((vals[j4*4+1] - mean) * inv * sm.par[384 + jj + 1] + sm.par[512 + jj + 1], 0.f);
            float v2 = fmaxf((vals[j4*4+2] - mean) * inv * sm.par[384 + jj + 2] + sm.par[512 + jj + 2], 0.f);
            float v3 = fmaxf((vals[j4*4+3] - mean) * inv * sm.par[384 + jj + 3] + sm.par[512 + jj + 3], 0.f);
            uint2 pk = make_uint2(pack2(v0, v1), pack2(v2, v3));
            *(uint2*)swzp(sm.x1, row, 768, 512 + seg * 64 + j4 * 8) = pk;
        }
    }
    lbar();

    f32x4 acc[2][4];
    #pragma unroll
    for (int nt = 0; nt < 2; ++nt)
        #pragma unroll
        for (int mt = 0; mt < 4; ++mt) acc[nt][mt] = (f32x4){0.f, 0.f, 0.f, 0.f};
    {
        const unsigned short* wp = W1bf + (size_t)(wave * 32 + llo) * 384 + lhi * 8;
        #pragma unroll
        for (int ks = 0; ks < 12; ++ks) {
            bf16x8 wf0 = *(const bf16x8*)(wp + ks * 32);
            bf16x8 wf1 = *(const bf16x8*)(wp + 16 * 384 + ks * 32);
            #pragma unroll
            for (int mt = 0; mt < 4; ++mt) {
                bf16x8 xf = *(const bf16x8*)swzp(sm.x1, mt * 16 + llo, 768, ks * 64 + lhi * 16);
                acc[0][mt] = MFMA(wf0, xf, acc[0][mt]);
                acc[1][mt] = MFMA(wf1, xf, acc[1][mt]);
            }
        }
    }
    {
        float4 b1q0 = *(const float4*)&b1[wave * 32 + lhi * 4];
        float4 b1q1 = *(const float4*)&b1[wave * 32 + 16 + lhi * 4];
        #pragma unroll
        for (int mt = 0; mt < 4; ++mt) {
            float s = 0.f, s2 = 0.f;
            #pragma unroll
            for (int r = 0; r < 4; ++r) {
                float v0 = acc[0][mt][r] + ((const float*)&b1q0)[r];
                float v1 = acc[1][mt][r] + ((const float*)&b1q1)[r];
                acc[0][mt][r] = v0; acc[1][mt][r] = v1;
                s += v0 + v1; s2 += v0 * v0 + v1 * v1;
            }
            s  += __shfl_xor(s, 16);  s  += __shfl_xor(s, 32);
            s2 += __shfl_xor(s2, 16); s2 += __shfl_xor(s2, 32);
            if (lane < 16) { sm.lns[mt * 16 + llo][wave] = s; sm.ln2[mt * 16 + llo][wave] = s2; }
        }
    }
    lbar();

    {
        float4 g1q0  = *(const float4*)&g1[wave * 32 + lhi * 4];
        float4 g1q1  = *(const float4*)&g1[wave * 32 + 16 + lhi * 4];
        float4 be1q0 = *(const float4*)&beta1[wave * 32 + lhi * 4];
        float4 be1q1 = *(const float4*)&beta1[wave * 32 + 16 + lhi * 4];
        #pragma unroll
        for (int mt = 0; mt < 4; ++mt) {
            int edge = mt * 16 + llo;
            size_t e = e0 + edge;
            float4 sa = *(const float4*)&sm.lns[edge][0];
            float4 ta = *(const float4*)&sm.ln2[edge][0];
            float s  = sa.x + sa.y + sa.z + sa.w;
            float s2 = ta.x + ta.y + ta.z + ta.w;
            float mean = s * (1.f / 128.f);
            float var  = fmaxf(s2 * (1.f / 128.f) - mean * mean, 0.f);
            float inv  = rsqrtf(var + 1e-5f);
            if (e < E_TOTAL) {
                #pragma unroll
                for (int nt = 0; nt < 2; ++nt) {
                    const float4& gq  = nt ? g1q1 : g1q0;
                    const float4& beq = nt ? be1q1 : be1q0;
                    float v0 = fmaxf((acc[nt][mt][0] - mean) * inv * gq.x + beq.x, 0.f);
                    float v1 = fmaxf((acc[nt][mt][1] - mean) * inv * gq.y + beq.y, 0.f);
                    float v2 = fmaxf((acc[nt][mt][2] - mean) * inv * gq.z + beq.z, 0.f);
                    float v3 = fmaxf((acc[nt][mt][3] - mean) * inv * gq.w + beq.w, 0.f);
                    uint2 pk = make_uint2(pack2(v0, v1), pack2(v2, v3));
                    int f = wave * 32 + nt * 16 + lhi * 4;
                    *(uint2*)(ybf + e * 128 + f) = pk;
                }
            }
        }
    }
}

// ---------------- K3: persistent GRU + blend + GEMM3 (bf16 h; 80 KB LDS; 2 blocks/CU) ----------------
// hbf aliases the xout region of d_out: each edge's hbf is read (prefetch) strictly
// before that edge's xout is written, by the same block -> safe & deterministic.
__global__ __launch_bounds__(512, 2) void gru_kernel(
    const unsigned short* __restrict__ ybf, const unsigned short* hbf,
    const float* __restrict__ bih, const float* __restrict__ bhh,
    const float* __restrict__ bx,
    const unsigned short* __restrict__ Wihbf, const unsigned short* __restrict__ Whhbf,
    const unsigned short* __restrict__ Wxbf,
    float* xout, float* __restrict__ hout)
{
    __shared__ unsigned short smy[2][64][128];   // y double buffer, 32 KB
    __shared__ unsigned short smh[2][64][128];   // h(bf16) double buffer, 32 KB
    __shared__ unsigned short smn[64][128];      // hnew, 16 KB
    const int tid  = threadIdx.x;
    const int wave = tid >> 6;        // 0..7; owns features [16w, 16w+16)
    const int lane = tid & 63;
    const int lhi  = lane >> 4;
    const int llo  = lane & 15;
    const int f    = wave * 16 + lhi * 4;       // GRU feature base
    const int fx   = (wave & 3) * 16 + lhi * 4; // GEMM3 feature base
    const int eh   = (wave >> 2) * 32;          // GEMM3 edge half

    // loop-invariant params (r,z biases pre-summed)
    float4 br_, bz_;
    {
        float4 a0 = *(const float4*)&bih[f],       c0 = *(const float4*)&bhh[f];
        float4 a1 = *(const float4*)&bih[128 + f], c1 = *(const float4*)&bhh[128 + f];
        br_.x = a0.x + c0.x; br_.y = a0.y + c0.y; br_.z = a0.z + c0.z; br_.w = a0.w + c0.w;
        bz_.x = a1.x + c1.x; bz_.y = a1.y + c1.y; bz_.z = a1.z + c1.z; bz_.w = a1.w + c1.w;
    }
    const float4 bi2 = *(const float4*)&bih[256 + f];
    const float4 bh2 = *(const float4*)&bhh[256 + f];
    const float4 bxq = *(const float4*)&bx[fx];
    const unsigned short* pi = Wihbf + (size_t)(wave * 16 + llo) * 128 + lhi * 8;
    const unsigned short* pw = Whhbf + (size_t)(wave * 16 + llo) * 128 + lhi * 8;
    const unsigned short* px = Wxbf + (size_t)((wave & 3) * 16 + llo) * 128 + lhi * 8;

    // DMA stage: inverse-swizzled global source -> linear LDS dest (rule #21)
    auto stage = [&](int t, int buf) {
        const size_t eb = (size_t)t * 64;
        #pragma unroll
        for (int j = 0; j < 2; ++j) {          // 2 rounds x 8 KB each for y and h
            int O = j * 8192 + tid * 16;
            int row = O >> 8, colB = O & 255;
            size_t e = eb + row; if (e >= E_TOTAL) e = E_TOTAL - 1;
            unsigned lc = (unsigned)colB ^ (((unsigned)row & 7u) << 4);
            __builtin_amdgcn_global_load_lds((GV*)((const char*)ybf + e * 256 + lc),
                                             (LV*)((char*)&smy[buf][0][0] + O), 16, 0, 0);
            __builtin_amdgcn_global_load_lds((GV*)((const char*)hbf + e * 256 + lc),
                                             (LV*)((char*)&smh[buf][0][0] + O), 16, 0, 0);
        }
    };

    int cur = 0;
    stage(blockIdx.x, 0);
    asm volatile("s_waitcnt vmcnt(0)" ::: "memory");
    lbar();

    for (int t = blockIdx.x; t < NTIL; t += GBLK) {
        const size_t e0 = (size_t)t * 64;
        {   // prefetch next tile into the other buffer
            int tn = t + GBLK; if (tn >= NTIL) tn = t;
            stage(tn, cur ^ 1);
        }

        // ---- GRU gates: acc[mt=4] per gate, weights from L2 ----
        f32x4 gr[4], gz[4], gn[4], gh[4];
        #pragma unroll
        for (int mt = 0; mt < 4; ++mt) {
            gr[mt] = (f32x4){0.f,0.f,0.f,0.f}; gz[mt] = (f32x4){0.f,0.f,0.f,0.f};
            gn[mt] = (f32x4){0.f,0.f,0.f,0.f}; gh[mt] = (f32x4){0.f,0.f,0.f,0.f};
        }
        #pragma unroll
        for (int ks = 0; ks < 4; ++ks) {
            bf16x8 wr = *(const bf16x8*)(pi + ks * 32);
            bf16x8 wz = *(const bf16x8*)(pi + 128 * 128 + ks * 32);
            bf16x8 wn = *(const bf16x8*)(pi + 256 * 128 + ks * 32);
            bf16x8 vr = *(const bf16x8*)(pw + ks * 32);
            bf16x8 vz = *(const bf16x8*)(pw + 128 * 128 + ks * 32);
            bf16x8 vn = *(const bf16x8*)(pw + 256 * 128 + ks * 32);
            #pragma unroll
            for (int mt = 0; mt < 4; ++mt) {
                int row = mt * 16 + llo;
                bf16x8 ay = *(const bf16x8*)swzp(smy[cur], row, 256, ks * 64 + lhi * 16);
                bf16x8 ah = *(const bf16x8*)swzp(smh[cur], row, 256, ks * 64 + lhi * 16);
                gr[mt] = MFMA(wr, ay, gr[mt]);  gr[mt] = MFMA(vr, ah, gr[mt]);
                gz[mt] = MFMA(wz, ay, gz[mt]);  gz[mt] = MFMA(vz, ah, gz[mt]);
                gn[mt] = MFMA(wn, ay, gn[mt]);  gh[mt] = MFMA(vn, ah, gh[mt]);
            }
        }

        // ---- epilogue: gates + blend (bf16 h) + hout store + hnew -> smn ----
        #pragma unroll
        for (int mt = 0; mt < 4; ++mt) {
            int row = mt * 16 + llo;
            ushort4 hp = *(const ushort4*)swzp(smh[cur], row, 256, 2 * f);
            float4 ho;
            #pragma unroll
            for (int r = 0; r < 4; ++r) {
                float rr = sigm(gr[mt][r] + ((const float*)&br_)[r]);
                float zz = sigm(gz[mt][r] + ((const float*)&bz_)[r]);
                float nn = tanh_fast(gn[mt][r] + ((const float*)&bi2)[r]
                                     + rr * (gh[mt][r] + ((const float*)&bh2)[r]));
                float hv = b2f(((const unsigned short*)&hp)[r]);
                ((float*)&ho)[r] = (1.f - zz) * nn + zz * hv;
            }
            unsigned int p0 = pack2(ho.x, ho.y), p1 = pack2(ho.z, ho.w);
            ushort4 pk;
            pk.x = (unsigned short)(p0 & 0xffffu); pk.y = (unsigned short)(p0 >> 16);
            pk.z = (unsigned short)(p1 & 0xffffu); pk.w = (unsigned short)(p1 >> 16);
            *(ushort4*)swzp(smn, row, 256, 2 * f) = pk;
            size_t e = e0 + row;
            if (e < E_TOTAL) *(float4*)(hout + e * 128 + f) = ho;
        }
        lbar();   // (C) hnew complete

        // ---- GEMM3: Wx rows [16(w&3),+16) x this wave's 32-edge half; direct xout ----
        {
            f32x4 a3[2];
            a3[0] = (f32x4){0.f,0.f,0.f,0.f}; a3[1] = (f32x4){0.f,0.f,0.f,0.f};
            #pragma unroll
            for (int ks = 0; ks < 4; ++ks) {
                bf16x8 wf = *(const bf16x8*)(px + ks * 32);
                #pragma unroll
                for (int mt = 0; mt < 2; ++mt) {
                    bf16x8 bh = *(const bf16x8*)swzp(smn, eh + mt * 16 + llo, 256, ks * 64 + lhi * 16);
                    a3[mt] = MFMA(wf, bh, a3[mt]);
                }
            }
            #pragma unroll
            for (int mt = 0; mt < 2; ++mt) {
                size_t e = e0 + eh + mt * 16 + llo;
                float4 o;
                o.x = a3[mt][0] + bxq.x; o.y = a3[mt][1] + bxq.y;
                o.z = a3[mt][2] + bxq.z; o.w = a3[mt][3] + bxq.w;
                if (e < E_TOTAL) *(float4*)(xout + e * 64 + fx) = o;
            }
        }

        // bottom: counted wait — 6 stores (4 hout + 2 xout) issued after the 4 DMA.
        // Tail tile has guarded (fewer) stores -> full drain there for safety.
        if (e0 + 64 <= E_TOTAL) asm volatile("s_waitcnt vmcnt(6)" ::: "memory");
        else                    asm volatile("s_waitcnt vmcnt(0)" ::: "memory");
        lbar();
        cur ^= 1;
    }
}

extern "C" void kernel_launch(void* const* d_in, const int* in_sizes, int n_in,
                              void* d_out, int out_size, void* d_ws, size_t ws_size,
                              hipStream_t stream)
{
    const float* src   = (const float*)d_in[0];
    const float* dst   = (const float*)d_in[1];
    const float* eat   = (const float*)d_in[2];
    const float* hin   = (const float*)d_in[3];
    const float* u     = (const float*)d_in[4];
    const int*   bat   = (const int*)d_in[5];
    const float* wind  = (const float*)d_in[6];
    const float* Ww    = (const float*)d_in[7];
    const float* bw    = (const float*)d_in[8];
    const float* gw    = (const float*)d_in[9];
    const float* betaw = (const float*)d_in[10];
    const float* W1    = (const float*)d_in[11];
    const float* b1    = (const float*)d_in[12];
    const float* g1    = (const float*)d_in[13];
    const float* beta1 = (const float*)d_in[14];
    const float* Wih   = (const float*)d_in[15];
    const float* Whh   = (const float*)d_in[16];
    const float* bih   = (const float*)d_in[17];
    const float* bhh   = (const float*)d_in[18];
    const float* Wx    = (const float*)d_in[19];
    const float* bx    = (const float*)d_in[20];

    // workspace: y (E*128 bf16 = 128 MB) | weights bf16 (304 KB)
    unsigned short* ybf  = (unsigned short*)d_ws;
    unsigned short* wbuf = ybf + 64000000ull;

    float* xout = (float*)d_out;
    float* hout = xout + (size_t)E_TOTAL * 64;
    // hbf lives in the xout region (exact 128 MB fit); read-before-write per edge in gru.
    unsigned short* hbf = (unsigned short*)d_out;

    wconv_kernel<<<608, 256, 0, stream>>>(W1, Wih, Whh, Wx, wbuf);

    mlp1_kernel<<<NB2, 256, 0, stream>>>(
        src, dst, eat, u, bat, wind, hin, Ww, bw, gw, betaw,
        b1, g1, beta1, wbuf, ybf, hbf);

    gru_kernel<<<GBLK, 512, 0, stream>>>(
        ybf, hbf, bih, bhh, bx,
        wbuf + 49152, wbuf + 98304, wbuf + 147456,
        xout, hout);
}